// Round 18
// baseline (1164.086 us; speedup 1.0000x reference)
//
#include <hip/hip_runtime.h>
#include <hip/hip_bf16.h>

typedef unsigned short u16;
typedef u16 us8 __attribute__((ext_vector_type(8)));
typedef u16 us4 __attribute__((ext_vector_type(4)));
typedef __bf16 bfx8 __attribute__((ext_vector_type(8)));
typedef float f32x4 __attribute__((ext_vector_type(4)));

#define EPS 1e-3f

__device__ __forceinline__ float bf2f(u16 u){ unsigned x = ((unsigned)u)<<16; return __builtin_bit_cast(float, x); }
__device__ __forceinline__ u16 f2bu(float f){ __hip_bfloat16 h = __float2bfloat16(f); return __builtin_bit_cast(u16, h); }
__device__ __forceinline__ bfx8 ldb8(const u16* p){ return __builtin_bit_cast(bfx8, *(const us8*)p); }

// five [9][64][64] f32 weight sets -> [9][64][64] bf16 (co-major), one launch
__global__ __launch_bounds__(256) void prepw5_k(
    const float* __restrict__ w0, const float* __restrict__ w1, const float* __restrict__ w2,
    const float* __restrict__ w3, const float* __restrict__ w4, u16* __restrict__ dst)
{
  int which = blockIdx.y;
  const float* src = which==0?w0:which==1?w1:which==2?w2:which==3?w3:w4;
  u16* d = dst + (size_t)which*36864;
  int idx = blockIdx.x*256 + threadIdx.x;
  if (idx < 36864){
    int ci = idx & 63; int rest = idx >> 6; int co = rest & 63; int t = rest >> 6;
    d[idx] = f2bu(src[((size_t)t*64 + ci)*64 + co]);
  }
}

// weights [9][CI][64] f32 -> [9][64][CI] bf16 (for wc, CI=512)
__global__ __launch_bounds__(256) void prepw_k(const float* __restrict__ src, u16* __restrict__ dst, int CI)
{
  int total = 9*CI*64;
  int idx = blockIdx.x*256 + threadIdx.x;
  if (idx < total){
    int ci = idx % CI; int rest = idx / CI; int co = rest & 63; int t = rest >> 6;
    dst[idx] = f2bu(src[((size_t)t*CI + ci)*64 + co]);
  }
}

// ---------------------------------------------------------------------------
// FUSED q/k/v MFMA 3x3 conv + per-channel stats partials, f32 input NHWC
// block 768 = 3 tensor-groups x 4 waves; tile = 2 rows x 128 x
// XCD swizzle; LDS-staged coalesced stores, 2-bit XOR bank spread {0,20,16,4}
// ---------------------------------------------------------------------------
__global__ __launch_bounds__(768) void conv_qkv_f32_k(
    const float* __restrict__ in,
    const u16* __restrict__ WtQ, const u16* __restrict__ WtK, const u16* __restrict__ WtV,
    const float* __restrict__ bq, const float* __restrict__ bk, const float* __restrict__ bv,
    u16* __restrict__ qo, u16* __restrict__ ko, u16* __restrict__ vo,
    float* __restrict__ partial)
{
  // flatten launch grid (2,128,8) -> bijective XCD chunk swizzle (nwg=2048)
  int lin = (blockIdx.z*128 + blockIdx.y)*2 + blockIdx.x;
  int swz = (lin & 7)*256 + (lin >> 3);
  int bx = swz & 1, by = (swz >> 1) & 127, bz = swz >> 8;
  int b = bz, y0 = by*2, x0 = bx*128;
  int tid = threadIdx.x, lane = tid & 63, wid = tid >> 6;   // wid 0..11
  int g3 = wid >> 2, wid4 = wid & 3;
  int l15 = lane & 15, lhi = lane >> 4;
  __shared__ u16 lds[4*130*64];

  for (int idx = tid; idx < 8320; idx += 768){
    int row = idx >> 4, c4 = idx & 15;
    int yy = row / 130, xx = row - yy*130;
    int gy = y0 + yy - 1, gx = x0 + xx - 1;
    us4 v = {0,0,0,0};
    if ((unsigned)gy < 256u && (unsigned)gx < 256u){
      float4 f = *(const float4*)(in + ((((size_t)b*256 + gy)*256 + gx)<<6) + c4*4);
      v[0] = f2bu(f.x); v[1] = f2bu(f.y); v[2] = f2bu(f.z); v[3] = f2bu(f.w);
    }
    *(us4*)(lds + row*64 + ((c4*4) ^ ((xx&7)<<3))) = v;
  }
  __syncthreads();

  const u16*  Wt   = (g3==0) ? WtQ : (g3==1) ? WtK : WtV;
  const float* bias = (g3==0) ? bq  : (g3==1) ? bk  : bv;

  f32x4 acc[2][2][4];
#pragma unroll
  for (int nf=0; nf<4; nf++){
    float bb = bias[nf*16 + l15];
#pragma unroll
    for (int ry=0; ry<2; ry++){
      acc[ry][0][nf] = (f32x4){bb,bb,bb,bb};
      acc[ry][1][nf] = (f32x4){bb,bb,bb,bb};
    }
  }
  int xbase = wid4*32;
#pragma unroll
  for (int ky=0; ky<3; ky++)
#pragma unroll
    for (int kx=0; kx<3; kx++){
      int t = ky*3 + kx;
      bfx8 bfr[2][4];
#pragma unroll
      for (int ks=0; ks<2; ks++)
#pragma unroll
        for (int nf=0; nf<4; nf++)
          bfr[ks][nf] = ldb8(Wt + ((t*64 + nf*16 + l15)<<6) + ks*32 + lhi*8);
#pragma unroll
      for (int ks=0; ks<2; ks++)
#pragma unroll
        for (int ry=0; ry<2; ry++)
#pragma unroll
          for (int mt=0; mt<2; mt++){
            int xx = xbase + mt*16 + l15 + kx;
            bfx8 a = ldb8(lds + ((ry+ky)*130 + xx)*64 + ((ks*32 + lhi*8) ^ ((xx&7)<<3)));
#pragma unroll
            for (int nf=0; nf<4; nf++)
              acc[ry][mt][nf] = __builtin_amdgcn_mfma_f32_16x16x32_bf16(a, bfr[ks][nf], acc[ry][mt][nf], 0,0,0);
          }
    }
  // epilogue: stage outputs in LDS ([3][128][72] u16), XOR col with
  // (((x&4)<<1)|((x&8)<<2)) -> lhi bank offsets {0,20,16,4}; coalesced stores.
  float s[4] = {0,0,0,0}, qs[4] = {0,0,0,0};
#pragma unroll
  for (int ry=0; ry<2; ry++){
    __syncthreads();
#pragma unroll
    for (int mt=0; mt<2; mt++){
      int xloc = xbase + mt*16 + lhi*4;
#pragma unroll
      for (int r=0; r<4; r++){
        int x = xloc + r;
        int xsw = ((x&4)<<1) | ((x&8)<<2);
#pragma unroll
        for (int nf=0; nf<4; nf++){
          u16 ub = f2bu(acc[ry][mt][nf][r]);
          lds[(g3*128 + x)*72 + ((nf*16 + l15) ^ xsw)] = ub;
          float vv = bf2f(ub);
          s[nf] += vv; qs[nf] += vv*vv;
        }
      }
    }
    __syncthreads();
    for (int idx = tid; idx < 3072; idx += 768){
      int row = idx >> 3, p8 = idx & 7;           // row = g*128 + xloc
      int g = row >> 7, xloc = row & 127;
      int xsw = ((row&4)<<1) | ((row&8)<<2);
      us8 v = *(const us8*)(lds + row*72 + ((p8*8) ^ xsw));
      u16* op = (g==0) ? qo : (g==1) ? ko : vo;
      *(us8*)(op + ((((size_t)b*256 + (y0+ry))*256 + (x0+xloc))<<6) + p8*8) = v;
    }
  }
  __syncthreads();
  float* smS = (float*)lds;          // [48][80] stride-80
  float* smQ = smS + 3840;
#pragma unroll
  for (int nf=0; nf<4; nf++){
    smS[(wid*4 + lhi)*80 + nf*16 + l15] = s[nf];
    smQ[(wid*4 + lhi)*80 + nf*16 + l15] = qs[nf];
  }
  __syncthreads();
  if (tid < 192){
    int tt = tid >> 6, c = tid & 63;
    float ssum = 0.f, qsum = 0.f;
#pragma unroll
    for (int w=0; w<16; w++){
      int slot = (tt*16 + w)*80 + c;
      ssum += smS[slot]; qsum += smQ[slot];
    }
    int blk = swz;                                   // 0..2047 (bijective)
    partial[(size_t)tt*262144 + (size_t)blk*128 + c]      = ssum;
    partial[(size_t)tt*262144 + (size_t)blk*128 + 64 + c] = qsum;
  }
}

// ---------------------------------------------------------------------------
// MFMA 3x3 conv, Cin=Cout=64, bf16 NHWC [8][64][256][64], 2 rows/block (+ReLU)
// BNIN: apply ss-BN to input during staging; STATS: fused output stats partials
// ---------------------------------------------------------------------------
template<bool RELU, bool BNIN, bool STATS>
__global__ __launch_bounds__(256) void conv2_mfma_k(
    const u16* __restrict__ in, const u16* __restrict__ Wt, const float* __restrict__ bias,
    const float* __restrict__ ssin, u16* __restrict__ out, float* __restrict__ partial)
{
  int b = blockIdx.z, y0 = blockIdx.y*2, x0 = blockIdx.x*128;
  int tid = threadIdx.x, lane = tid & 63, wid = tid >> 6;
  int l15 = lane & 15, lhi = lane >> 4;
  __shared__ u16 lds[4*130*64];
  __shared__ float ssm[128];
  if (BNIN){
    if (tid < 128) ssm[tid] = ssin[tid];
    __syncthreads();
  }

  for (int idx = tid; idx < 4160; idx += 256){
    int row = idx >> 3, ch = idx & 7;
    int yy = row / 130, xx = row - yy*130;
    int gy = y0 + yy - 1, gx = x0 + xx - 1;
    us8 w = {0,0,0,0,0,0,0,0};
    if ((unsigned)gy < 64u && (unsigned)gx < 256u){
      us8 v = *(const us8*)(in + ((((size_t)b*64 + gy)*256 + gx)<<6) + ch*8);
      if (BNIN){
#pragma unroll
        for (int e=0; e<8; e++){
          int ci = ch*8 + e;
          w[e] = f2bu(bf2f(v[e])*ssm[ci] + ssm[64+ci]);
        }
      } else w = v;
    }
    *(us8*)(lds + row*64 + ((ch*8) ^ ((xx&7)<<3))) = w;
  }
  __syncthreads();

  f32x4 acc[2][2][4];
#pragma unroll
  for (int nf=0; nf<4; nf++){
    float bb = bias[nf*16 + l15];
#pragma unroll
    for (int ry=0; ry<2; ry++){
      acc[ry][0][nf] = (f32x4){bb,bb,bb,bb};
      acc[ry][1][nf] = (f32x4){bb,bb,bb,bb};
    }
  }
  int xbase = wid*32;
#pragma unroll
  for (int ky=0; ky<3; ky++)
#pragma unroll
    for (int kx=0; kx<3; kx++){
      int t = ky*3 + kx;
      bfx8 bfr[2][4];
#pragma unroll
      for (int ks=0; ks<2; ks++)
#pragma unroll
        for (int nf=0; nf<4; nf++)
          bfr[ks][nf] = ldb8(Wt + ((t*64 + nf*16 + l15)<<6) + ks*32 + lhi*8);
#pragma unroll
      for (int ks=0; ks<2; ks++)
#pragma unroll
        for (int ry=0; ry<2; ry++)
#pragma unroll
          for (int mt=0; mt<2; mt++){
            int xx = xbase + mt*16 + l15 + kx;
            bfx8 a = ldb8(lds + ((ry+ky)*130 + xx)*64 + ((ks*32 + lhi*8) ^ ((xx&7)<<3)));
#pragma unroll
            for (int nf=0; nf<4; nf++)
              acc[ry][mt][nf] = __builtin_amdgcn_mfma_f32_16x16x32_bf16(a, bfr[ks][nf], acc[ry][mt][nf], 0,0,0);
          }
    }
  float s[4] = {0,0,0,0}, qs[4] = {0,0,0,0};
#pragma unroll
  for (int ry=0; ry<2; ry++)
#pragma unroll
    for (int mt=0; mt<2; mt++)
#pragma unroll
      for (int nf=0; nf<4; nf++)
#pragma unroll
        for (int r=0; r<4; r++){
          int x = x0 + xbase + mt*16 + lhi*4 + r;
          float vv = acc[ry][mt][nf][r];
          if (RELU) vv = fmaxf(vv, 0.f);
          u16 ub = f2bu(vv);
          out[((((size_t)b*64 + (y0+ry))*256 + x)<<6) + nf*16 + l15] = ub;
          if (STATS){
            float vb = bf2f(ub);
            s[nf] += vb; qs[nf] += vb*vb;
          }
        }
  if (STATS){
    __syncthreads();
    float* smS = (float*)lds;        // [16][80] stride-80
    float* smQ = smS + 1280;
#pragma unroll
    for (int nf=0; nf<4; nf++){
      smS[(wid*4 + lhi)*80 + nf*16 + l15] = s[nf];
      smQ[(wid*4 + lhi)*80 + nf*16 + l15] = qs[nf];
    }
    __syncthreads();
    if (tid < 64){
      float ssum = 0.f, qsum = 0.f;
#pragma unroll
      for (int w=0; w<16; w++){
        ssum += smS[w*80 + tid]; qsum += smQ[w*80 + tid];
      }
      int blk = (blockIdx.z*32 + blockIdx.y)*2 + blockIdx.x;   // 0..511
      partial[(size_t)blk*128 + tid]      = ssum;
      partial[(size_t)blk*128 + 64 + tid] = qsum;
    }
  }
}

// ---------------------------------------------------------------------------
// MFMA conv on cat [8][64][256][512] -> +bias -> LayerNorm(64), 2 rows/block
// ---------------------------------------------------------------------------
__global__ __launch_bounds__(256) void conv_cat_ln_k(
    const u16* __restrict__ in, const u16* __restrict__ Wt, const float* __restrict__ bias,
    const float* __restrict__ lng, const float* __restrict__ lnb, u16* __restrict__ out)
{
  int b = blockIdx.z, y0 = blockIdx.y*2, x0 = blockIdx.x*128;
  int tid = threadIdx.x, lane = tid & 63, wid = tid >> 6;
  int l15 = lane & 15, lhi = lane >> 4;
  __shared__ u16 lds[4*130*64];

  f32x4 acc[2][2][4];
#pragma unroll
  for (int nf=0; nf<4; nf++){
    float bb = bias[nf*16 + l15];
#pragma unroll
    for (int ry=0; ry<2; ry++){
      acc[ry][0][nf] = (f32x4){bb,bb,bb,bb};
      acc[ry][1][nf] = (f32x4){bb,bb,bb,bb};
    }
  }
  int xbase = wid*32;
  for (int ci0 = 0; ci0 < 512; ci0 += 64){
    __syncthreads();
    for (int idx = tid; idx < 4160; idx += 256){
      int row = idx >> 3, ch = idx & 7;
      int yy = row / 130, xx = row - yy*130;
      int gy = y0 + yy - 1, gx = x0 + xx - 1;
      us8 v = {0,0,0,0,0,0,0,0};
      if ((unsigned)gy < 64u && (unsigned)gx < 256u)
        v = *(const us8*)(in + ((((size_t)b*64 + gy)*256 + gx)<<9) + ci0 + ch*8);
      *(us8*)(lds + row*64 + ((ch*8) ^ ((xx&7)<<3))) = v;
    }
    __syncthreads();
#pragma unroll
    for (int ky=0; ky<3; ky++)
#pragma unroll
      for (int kx=0; kx<3; kx++){
        int t = ky*3 + kx;
        bfx8 bfr[2][4];
#pragma unroll
        for (int ks=0; ks<2; ks++)
#pragma unroll
          for (int nf=0; nf<4; nf++)
            bfr[ks][nf] = ldb8(Wt + ((size_t)(t*64 + nf*16 + l15)<<9) + ci0 + ks*32 + lhi*8);
#pragma unroll
        for (int ks=0; ks<2; ks++)
#pragma unroll
          for (int ry=0; ry<2; ry++)
#pragma unroll
            for (int mt=0; mt<2; mt++){
              int xx = xbase + mt*16 + l15 + kx;
              bfx8 a = ldb8(lds + ((ry+ky)*130 + xx)*64 + ((ks*32 + lhi*8) ^ ((xx&7)<<3)));
#pragma unroll
              for (int nf=0; nf<4; nf++)
                acc[ry][mt][nf] = __builtin_amdgcn_mfma_f32_16x16x32_bf16(a, bfr[ks][nf], acc[ry][mt][nf], 0,0,0);
            }
      }
  }
  float lg[4], lb[4];
#pragma unroll
  for (int nf=0; nf<4; nf++){ lg[nf] = lng[nf*16+l15]; lb[nf] = lnb[nf*16+l15]; }
#pragma unroll
  for (int ry=0; ry<2; ry++)
#pragma unroll
    for (int mt=0; mt<2; mt++)
#pragma unroll
      for (int r=0; r<4; r++){
        float v0 = acc[ry][mt][0][r], v1 = acc[ry][mt][1][r], v2 = acc[ry][mt][2][r], v3 = acc[ry][mt][3][r];
        float s = v0+v1+v2+v3;
        s += __shfl_xor(s,1); s += __shfl_xor(s,2); s += __shfl_xor(s,4); s += __shfl_xor(s,8);
        float m = s * 0.015625f;
        float d0=v0-m, d1=v1-m, d2=v2-m, d3=v3-m;
        float q = d0*d0+d1*d1+d2*d2+d3*d3;
        q += __shfl_xor(q,1); q += __shfl_xor(q,2); q += __shfl_xor(q,4); q += __shfl_xor(q,8);
        float rs = rsqrtf(q*0.015625f + EPS);
        int x = x0 + xbase + mt*16 + lhi*4 + r;
        size_t base = ((((size_t)b*64 + (y0+ry))*256 + x)<<6) + l15;
        out[base]    = f2bu(d0*rs*lg[0] + lb[0]);
        out[base+16] = f2bu(d1*rs*lg[1] + lb[1]);
        out[base+32] = f2bu(d2*rs*lg[2] + lb[2]);
        out[base+48] = f2bu(d3*rs*lg[3] + lb[3]);
      }
}

// grid 3: block tt finalizes tensor tt's 2048 partials (from conv_qkv epilogue)
__global__ __launch_bounds__(256) void finalize3_k(const float* __restrict__ partial,
    const float* __restrict__ gq, const float* __restrict__ bq,
    const float* __restrict__ gk, const float* __restrict__ bk,
    const float* __restrict__ gv, const float* __restrict__ bv,
    float inv_count, float* __restrict__ ssbase)
{
  int tt = blockIdx.x;
  const float* part = partial + (size_t)tt*262144;
  const float* g  = (tt==0)?gq:(tt==1)?gk:gv;
  const float* be = (tt==0)?bq:(tt==1)?bk:bv;
  float* ss = ssbase + tt*128;
  __shared__ float sm[4][128];
  int c = threadIdx.x & 63, qq = threadIdx.x >> 6;
  float s = 0.f, v = 0.f;
  for (int i = qq*512; i < qq*512+512; i++){ s += part[i*128 + c]; v += part[i*128 + 64 + c]; }
  sm[qq][c] = s; sm[qq][64+c] = v;
  __syncthreads();
  if (qq == 0){
    s = sm[0][c]+sm[1][c]+sm[2][c]+sm[3][c];
    v = sm[0][64+c]+sm[1][64+c]+sm[2][64+c]+sm[3][64+c];
    float m = s*inv_count;
    float var = v*inv_count - m*m;
    float sc = g[c]*rsqrtf(var + EPS);
    ss[c] = sc; ss[64+c] = be[c] - m*sc;
  }
}

// finalizes 512 partials (from conv2 fused stats)
__global__ __launch_bounds__(256) void finalize512_k(const float* __restrict__ partial,
                                                     const float* __restrict__ g, const float* __restrict__ beta,
                                                     float inv_count, float* __restrict__ ss)
{
  __shared__ float sm[4][128];
  int c = threadIdx.x & 63, qq = threadIdx.x >> 6;
  float s = 0.f, v = 0.f;
  for (int i = qq*128; i < qq*128+128; i++){ s += partial[i*128 + c]; v += partial[i*128 + 64 + c]; }
  sm[qq][c] = s; sm[qq][64+c] = v;
  __syncthreads();
  if (qq == 0){
    s = sm[0][c]+sm[1][c]+sm[2][c]+sm[3][c];
    v = sm[0][64+c]+sm[1][64+c]+sm[2][64+c]+sm[3][64+c];
    float m = s*inv_count;
    float var = v*inv_count - m*m;
    float sc = g[c]*rsqrtf(var + EPS);
    ss[c] = sc; ss[64+c] = beta[c] - m*sc;
  }
}

// ---------------------------------------------------------------------------
// BN-fused transpose, all 3 tensors in one launch; us8 global r/w
// grid (4, 256, 24): z -> tt = z>>3 (tensor), b = z&7
__global__ __launch_bounds__(256) void bn_tr3_k(const u16* __restrict__ xbase,
                                                const float* __restrict__ ssbase,
                                                u16* __restrict__ xTbase)
{
  int z = blockIdx.z, tt = z >> 3, b = z & 7;
  const u16* x = xbase + (size_t)tt*33554432;
  const float* ss = ssbase + tt*128;
  u16* xT = xTbase + (size_t)tt*33554432;
  int t = blockIdx.y, f0 = blockIdx.x*64;
  __shared__ float sm[64][65];
  int tid = threadIdx.x;
  for (int idx = tid; idx < 512; idx += 256){
    int fi = idx >> 3, cg = idx & 7;
    us8 v = *(const us8*)(x + ((((size_t)b*256 + t)*256 + f0 + fi)<<6) + cg*8);
#pragma unroll
    for (int e=0; e<8; e++){
      int ci = cg*8 + e;
      sm[fi][ci] = bf2f(v[e])*ss[ci] + ss[64+ci];
    }
  }
  __syncthreads();
  for (int idx = tid; idx < 512; idx += 256){
    int ci = idx >> 3, fg = idx & 7;
    us8 o;
#pragma unroll
    for (int e=0; e<8; e++) o[e] = f2bu(sm[fg*8+e][ci]);
    *(us8*)(xT + (((size_t)b*64 + ci)<<16) + t*256 + f0 + fg*8) = o;
  }
}

// ---------------------------------------------------------------------------
// MFMA GEMM: C[bc][i][n] = scale * sum_k A(i,k)*B(n,k), 256x256x256 per bc
// C staged through (dead) Al/Bl LDS -> coalesced 256B-per-row stores
template<bool TRA, bool TRB>
__global__ __launch_bounds__(256) void gemm_k(const u16* __restrict__ A, const u16* __restrict__ B,
                                              u16* __restrict__ C, float scale,
                                              int ldC, size_t cBatch, int cOff)
{
  int bc = blockIdx.z;
  const u16* Ab = A + ((size_t)bc<<16);
  const u16* Bb = B + ((size_t)bc<<16);
  u16* Cb = C + (size_t)bc*cBatch + cOff;
  int i0 = blockIdx.y*128, j0 = blockIdx.x*128;
  int tid = threadIdx.x, lane = tid & 63, wid = tid >> 6;
  int l15 = lane & 15, lhi = lane >> 4;
  __shared__ u16 sh[16384];             // Al = sh[0:8192], Bl = sh[8192:16384]
  u16* Al = sh;
  u16* Bl = sh + 8192;
  f32x4 acc[2][8] = {};

  for (int k0 = 0; k0 < 256; k0 += 64){
    __syncthreads();
    if (!TRA){
      for (int idx = tid; idx < 1024; idx += 256){
        int r = idx >> 3, c8 = idx & 7;
        us8 v = *(const us8*)(Ab + (size_t)(i0+r)*256 + k0 + c8*8);
        *(us8*)(Al + r*64 + ((c8*8) ^ ((r&7)<<3))) = v;
      }
    } else {
      for (int idx = tid; idx < 1024; idx += 256){
        int kr = idx >> 4, c8 = idx & 15;
        us8 v = *(const us8*)(Ab + (size_t)(k0+kr)*256 + i0 + c8*8);
#pragma unroll
        for (int e=0; e<8; e++){
          int i = c8*8 + e;
          Al[i*64 + (kr ^ ((i&7)<<3))] = v[e];
        }
      }
    }
    if (!TRB){
      for (int idx = tid; idx < 1024; idx += 256){
        int r = idx >> 3, c8 = idx & 7;
        us8 v = *(const us8*)(Bb + (size_t)(j0+r)*256 + k0 + c8*8);
        *(us8*)(Bl + r*64 + ((c8*8) ^ ((r&7)<<3))) = v;
      }
    } else {
      for (int idx = tid; idx < 1024; idx += 256){
        int kr = idx >> 4, c8 = idx & 15;
        us8 v = *(const us8*)(Bb + (size_t)(k0+kr)*256 + j0 + c8*8);
#pragma unroll
        for (int e=0; e<8; e++){
          int j = c8*8 + e;
          Bl[j*64 + (kr ^ ((j&7)<<3))] = v[e];
        }
      }
    }
    __syncthreads();
    int wrow = wid*32;
#pragma unroll
    for (int ks=0; ks<2; ks++){
      bfx8 bfr[8];
#pragma unroll
      for (int nf=0; nf<8; nf++)
        bfr[nf] = ldb8(Bl + (nf*16+l15)*64 + ((ks*32 + lhi*8) ^ ((l15&7)<<3)));
#pragma unroll
      for (int mt=0; mt<2; mt++){
        int r = wrow + mt*16 + l15;
        bfx8 a = ldb8(Al + r*64 + ((ks*32 + lhi*8) ^ ((r&7)<<3)));
#pragma unroll
        for (int nf=0; nf<8; nf++)
          acc[mt][nf] = __builtin_amdgcn_mfma_f32_16x16x32_bf16(a, bfr[nf], acc[mt][nf], 0,0,0);
      }
    }
  }
  // C epilogue: stage 128x128 tile in sh (XOR bank spread), coalesced stores
  __syncthreads();
#pragma unroll
  for (int mt=0; mt<2; mt++)
#pragma unroll
    for (int r=0; r<4; r++){
      int iloc = wid*32 + mt*16 + lhi*4 + r;
      int xsw = ((iloc&4)<<1) | ((iloc&8)<<2);
#pragma unroll
      for (int nf=0; nf<8; nf++)
        sh[iloc*128 + ((nf*16 + l15) ^ xsw)] = f2bu(acc[mt][nf][r]*scale);
    }
  __syncthreads();
  for (int idx = tid; idx < 2048; idx += 256){
    int iloc = idx >> 4, p8 = idx & 15;
    int xsw = ((iloc&4)<<1) | ((iloc&8)<<2);
    us8 v = *(const us8*)(sh + iloc*128 + ((p8*8) ^ xsw));
    *(us8*)(Cb + (size_t)(i0+iloc)*ldC + j0 + p8*8) = v;
  }
}

// softmax over rows of 256 (one wave per row), in-place
__global__ __launch_bounds__(256) void softmax_k(u16* __restrict__ P)
{
  size_t row = (size_t)blockIdx.x*4 + (threadIdx.x >> 6);
  int lane = threadIdx.x & 63;
  u16* p = P + row*256 + lane*4;
  us4 u = *(us4*)p;
  float v[4];
#pragma unroll
  for (int e=0; e<4; e++) v[e] = bf2f(u[e]);
  float m = fmaxf(fmaxf(v[0],v[1]), fmaxf(v[2],v[3]));
  for (int off=1; off<64; off<<=1) m = fmaxf(m, __shfl_xor(m, off));
  float s = 0.f;
#pragma unroll
  for (int e=0; e<4; e++){ v[e] = __expf(v[e]-m); s += v[e]; }
  for (int off=1; off<64; off<<=1) s += __shfl_xor(s, off);
  float inv = 1.f/s;
  us4 o;
#pragma unroll
  for (int e=0; e<4; e++) o[e] = f2bu(v[e]*inv);
  *(us4*)p = o;
}

__global__ __launch_bounds__(256) void apply_bn_f_k(const u16* __restrict__ x, const float* __restrict__ ss,
                                                    float* __restrict__ out, int n4)
{
  int i = blockIdx.x*256 + threadIdx.x;
  if (i < n4){
    int c0 = (i & 15)*4;
    us4 u = ((const us4*)x)[i];
    float4 o;
    o.x = bf2f(u[0])*ss[c0]   + ss[64+c0];
    o.y = bf2f(u[1])*ss[c0+1] + ss[64+c0+1];
    o.z = bf2f(u[2])*ss[c0+2] + ss[64+c0+2];
    o.w = bf2f(u[3])*ss[c0+3] + ss[64+c0+3];
    ((float4*)out)[i] = o;
  }
}

// ---------------------------------------------------------------------------
extern "C" void kernel_launch(void* const* d_in, const int* in_sizes, int n_in,
                              void* d_out, int out_size, void* d_ws, size_t ws_size,
                              hipStream_t stream)
{
  const float* in    = (const float*)d_in[0];
  const float* wq    = (const float*)d_in[1];  const float* bq    = (const float*)d_in[2];
  const float* wk    = (const float*)d_in[3];  const float* bk    = (const float*)d_in[4];
  const float* wv    = (const float*)d_in[5];  const float* bv    = (const float*)d_in[6];
  const float* gq    = (const float*)d_in[7];  const float* betaq = (const float*)d_in[8];
  const float* gk    = (const float*)d_in[9];  const float* betak = (const float*)d_in[10];
  const float* gv    = (const float*)d_in[11]; const float* betav = (const float*)d_in[12];
  const float* wc    = (const float*)d_in[13]; const float* bcv   = (const float*)d_in[14];
  const float* lng   = (const float*)d_in[15]; const float* lnb   = (const float*)d_in[16];
  const float* w1    = (const float*)d_in[17]; const float* b1    = (const float*)d_in[18];
  const float* g1    = (const float*)d_in[19]; const float* beta1 = (const float*)d_in[20];
  const float* w2    = (const float*)d_in[21]; const float* b2    = (const float*)d_in[22];
  const float* g2    = (const float*)d_in[23]; const float* beta2 = (const float*)d_in[24];
  float* out = (float*)d_out;

  char* ws = (char*)d_ws;
  const size_t MB = 1ull<<20;
  // Layout (reuse only after last read; input never copied):
  //   0..64    qraw -> P1
  //   64..128  kraw -> P2        (P1,P2 contiguous: single softmax launch)
  //   128..192 vraw -> y0(128..144), f1(144..160), rr(160..176)
  //   192..256 qT  --\ cat = 192..320
  //   256..320 kT  --/
  //   320..384 vT   (partial @352, 3MB: conv_qkv writes -> finalize3 reads,
  //                  all before bn_tr3 writes vT; conv2 stats rewrite it after
  //                  vT is dead)
  //   384+     ss (5x128) + prepped weights (~1.2MB)
  u16* qraw = (u16*)(ws);
  u16* kraw = (u16*)(ws + 64*MB);
  u16* vraw = (u16*)(ws + 128*MB);
  u16* qT   = (u16*)(ws + 192*MB);
  u16* kT   = (u16*)(ws + 256*MB);
  u16* vT   = (u16*)(ws + 320*MB);
  u16* P1   = qraw;
  u16* P2   = kraw;
  u16* cat  = qT;
  u16* y0   = (u16*)(ws + 128*MB);
  u16* f1   = (u16*)(ws + 144*MB);
  u16* rr   = (u16*)(ws + 160*MB);
  float* partial = (float*)(ws + 352*MB);            // 3MB (3 x 2048 x 128)
  float* ssq = (float*)(ws + 384*MB);                // ssq,ssk,ssv contiguous
  float* ss1 = ssq + 384;  float* ss2 = ssq + 512;
  u16* wqT = (u16*)(ws + 384*MB + 4096);             // 5 x 36864 contiguous + wcT
  u16* wkT = wqT + 36864; u16* wvT = wkT + 36864;
  u16* w1T = wvT + 36864; u16* w2T = w1T + 36864;
  u16* wcT = w2T + 36864;                            // 294912 elems

  dim3 blk(256);
  dim3 blk768(768);

  prepw5_k<<<dim3(144,5), blk, 0, stream>>>(wq, wk, wv, w1, w2, wqT);
  prepw_k<<<1152, blk, 0, stream>>>(wc, wcT, 512);

  const float invN1 = 1.f/524288.f;
  conv_qkv_f32_k<<<dim3(2,128,8), blk768, 0, stream>>>(in, wqT,wkT,wvT, bq,bk,bv,
                                                       qraw,kraw,vraw, partial);
  finalize3_k<<<3, blk, 0, stream>>>(partial, gq,betaq, gk,betak, gv,betav, invN1, ssq);
  bn_tr3_k<<<dim3(4,256,24), blk, 0, stream>>>(qraw, ssq, qT);

  // scores: time (row-major both), freq (k-major both)
  gemm_k<false,false><<<dim3(2,2,512), blk, 0, stream>>>(qT, kT, P1, 0.0625f, 256, 65536, 0);
  gemm_k<true ,true ><<<dim3(2,2,512), blk, 0, stream>>>(qT, kT, P2, 0.0625f, 256, 65536, 0);
  softmax_k<<<65536, blk, 0, stream>>>(P1);   // P1 and P2 are contiguous
  // AV: time C[t][f] = sum_j P1[t][j] vT[j][f] -> TRB=true
  //     freq C[f][t] = sum_j P2[f][j] vT[t][j] -> TRB=false
  gemm_k<false,true ><<<dim3(2,2,512), blk, 0, stream>>>(P1, vT, cat, 1.f, 512, 131072, 0);
  gemm_k<false,false><<<dim3(2,2,512), blk, 0, stream>>>(P2, vT, cat, 1.f, 512, 131072, 256);

  conv_cat_ln_k<<<dim3(2,32,8), blk, 0, stream>>>(cat, wcT, bcv, lng, lnb, y0);

  const float invN2 = 1.f/131072.f;
  conv2_mfma_k<true,false,true><<<dim3(2,32,8), blk, 0, stream>>>(y0, w1T, b1, ssq, rr, partial);
  finalize512_k<<<1, blk, 0, stream>>>(partial, g1, beta1, invN2, ss1);

  conv2_mfma_k<true,true,true><<<dim3(2,32,8), blk, 0, stream>>>(rr, w2T, b2, ss1, f1, partial);
  finalize512_k<<<1, blk, 0, stream>>>(partial, g2, beta2, invN2, ss2);
  apply_bn_f_k<<<8192, blk, 0, stream>>>(f1, ss2, out, 2097152);
}

// Round 19
// 1157.593 us; speedup vs baseline: 1.0056x; 1.0056x over previous
//
#include <hip/hip_runtime.h>
#include <hip/hip_bf16.h>

typedef unsigned short u16;
typedef u16 us8 __attribute__((ext_vector_type(8)));
typedef u16 us4 __attribute__((ext_vector_type(4)));
typedef __bf16 bfx8 __attribute__((ext_vector_type(8)));
typedef float f32x4 __attribute__((ext_vector_type(4)));

#define EPS 1e-3f

__device__ __forceinline__ float bf2f(u16 u){ unsigned x = ((unsigned)u)<<16; return __builtin_bit_cast(float, x); }
__device__ __forceinline__ u16 f2bu(float f){ __hip_bfloat16 h = __float2bfloat16(f); return __builtin_bit_cast(u16, h); }
__device__ __forceinline__ bfx8 ldb8(const u16* p){ return __builtin_bit_cast(bfx8, *(const us8*)p); }

// five [9][64][64] f32 weight sets -> [9][64][64] bf16 (co-major), one launch
__global__ __launch_bounds__(256) void prepw5_k(
    const float* __restrict__ w0, const float* __restrict__ w1, const float* __restrict__ w2,
    const float* __restrict__ w3, const float* __restrict__ w4, u16* __restrict__ dst)
{
  int which = blockIdx.y;
  const float* src = which==0?w0:which==1?w1:which==2?w2:which==3?w3:w4;
  u16* d = dst + (size_t)which*36864;
  int idx = blockIdx.x*256 + threadIdx.x;
  if (idx < 36864){
    int ci = idx & 63; int rest = idx >> 6; int co = rest & 63; int t = rest >> 6;
    d[idx] = f2bu(src[((size_t)t*64 + ci)*64 + co]);
  }
}

// weights [9][CI][64] f32 -> [9][64][CI] bf16 (for wc, CI=512)
__global__ __launch_bounds__(256) void prepw_k(const float* __restrict__ src, u16* __restrict__ dst, int CI)
{
  int total = 9*CI*64;
  int idx = blockIdx.x*256 + threadIdx.x;
  if (idx < total){
    int ci = idx % CI; int rest = idx / CI; int co = rest & 63; int t = rest >> 6;
    dst[idx] = f2bu(src[((size_t)t*CI + ci)*64 + co]);
  }
}

// ---------------------------------------------------------------------------
// FUSED q/k/v MFMA 3x3 conv + per-channel stats partials, f32 input NHWC
// block 768 = 3 tensor-groups x 4 waves; tile = 2 rows x 128 x
// XCD-aware block swizzle; outputs staged through LDS -> coalesced 128B stores
// ---------------------------------------------------------------------------
__global__ __launch_bounds__(768) void conv_qkv_f32_k(
    const float* __restrict__ in,
    const u16* __restrict__ WtQ, const u16* __restrict__ WtK, const u16* __restrict__ WtV,
    const float* __restrict__ bq, const float* __restrict__ bk, const float* __restrict__ bv,
    u16* __restrict__ qo, u16* __restrict__ ko, u16* __restrict__ vo,
    float* __restrict__ partial)
{
  // flatten launch grid (2,128,8) -> bijective XCD chunk swizzle (nwg=2048)
  int lin = (blockIdx.z*128 + blockIdx.y)*2 + blockIdx.x;
  int swz = (lin & 7)*256 + (lin >> 3);
  int bx = swz & 1, by = (swz >> 1) & 127, bz = swz >> 8;
  int b = bz, y0 = by*2, x0 = bx*128;
  int tid = threadIdx.x, lane = tid & 63, wid = tid >> 6;   // wid 0..11
  int g3 = wid >> 2, wid4 = wid & 3;
  int l15 = lane & 15, lhi = lane >> 4;
  __shared__ u16 lds[4*130*64];

  for (int idx = tid; idx < 8320; idx += 768){
    int row = idx >> 4, c4 = idx & 15;
    int yy = row / 130, xx = row - yy*130;
    int gy = y0 + yy - 1, gx = x0 + xx - 1;
    us4 v = {0,0,0,0};
    if ((unsigned)gy < 256u && (unsigned)gx < 256u){
      float4 f = *(const float4*)(in + ((((size_t)b*256 + gy)*256 + gx)<<6) + c4*4);
      v[0] = f2bu(f.x); v[1] = f2bu(f.y); v[2] = f2bu(f.z); v[3] = f2bu(f.w);
    }
    *(us4*)(lds + row*64 + ((c4*4) ^ ((xx&7)<<3))) = v;
  }
  __syncthreads();

  const u16*  Wt   = (g3==0) ? WtQ : (g3==1) ? WtK : WtV;
  const float* bias = (g3==0) ? bq  : (g3==1) ? bk  : bv;

  f32x4 acc[2][2][4];
#pragma unroll
  for (int nf=0; nf<4; nf++){
    float bb = bias[nf*16 + l15];
#pragma unroll
    for (int ry=0; ry<2; ry++){
      acc[ry][0][nf] = (f32x4){bb,bb,bb,bb};
      acc[ry][1][nf] = (f32x4){bb,bb,bb,bb};
    }
  }
  int xbase = wid4*32;
#pragma unroll
  for (int ky=0; ky<3; ky++)
#pragma unroll
    for (int kx=0; kx<3; kx++){
      int t = ky*3 + kx;
      bfx8 bfr[2][4];
#pragma unroll
      for (int ks=0; ks<2; ks++)
#pragma unroll
        for (int nf=0; nf<4; nf++)
          bfr[ks][nf] = ldb8(Wt + ((t*64 + nf*16 + l15)<<6) + ks*32 + lhi*8);
#pragma unroll
      for (int ks=0; ks<2; ks++)
#pragma unroll
        for (int ry=0; ry<2; ry++)
#pragma unroll
          for (int mt=0; mt<2; mt++){
            int xx = xbase + mt*16 + l15 + kx;
            bfx8 a = ldb8(lds + ((ry+ky)*130 + xx)*64 + ((ks*32 + lhi*8) ^ ((xx&7)<<3)));
#pragma unroll
            for (int nf=0; nf<4; nf++)
              acc[ry][mt][nf] = __builtin_amdgcn_mfma_f32_16x16x32_bf16(a, bfr[ks][nf], acc[ry][mt][nf], 0,0,0);
          }
    }
  // epilogue: stage outputs in LDS ([3][128][72] u16, stride-72 = 2 lanes/bank,
  // 144B rows keep us8 16B-aligned), then coalesced 128B global stores.
  float s[4] = {0,0,0,0}, qs[4] = {0,0,0,0};
#pragma unroll
  for (int ry=0; ry<2; ry++){
    __syncthreads();
#pragma unroll
    for (int mt=0; mt<2; mt++)
#pragma unroll
      for (int nf=0; nf<4; nf++)
#pragma unroll
        for (int r=0; r<4; r++){
          int xloc = xbase + mt*16 + lhi*4 + r;
          u16 ub = f2bu(acc[ry][mt][nf][r]);
          lds[(g3*128 + xloc)*72 + nf*16 + l15] = ub;
          float vv = bf2f(ub);
          s[nf] += vv; qs[nf] += vv*vv;
        }
    __syncthreads();
    for (int idx = tid; idx < 3072; idx += 768){
      int row = idx >> 3, p8 = idx & 7;           // row = g*128 + xloc
      int g = row >> 7, xloc = row & 127;
      us8 v = *(const us8*)(lds + row*72 + p8*8);
      u16* op = (g==0) ? qo : (g==1) ? ko : vo;
      *(us8*)(op + ((((size_t)b*256 + (y0+ry))*256 + (x0+xloc))<<6) + p8*8) = v;
    }
  }
  __syncthreads();
  float* smS = (float*)lds;          // [48][80] stride-80
  float* smQ = smS + 3840;
#pragma unroll
  for (int nf=0; nf<4; nf++){
    smS[(wid*4 + lhi)*80 + nf*16 + l15] = s[nf];
    smQ[(wid*4 + lhi)*80 + nf*16 + l15] = qs[nf];
  }
  __syncthreads();
  if (tid < 192){
    int tt = tid >> 6, c = tid & 63;
    float ssum = 0.f, qsum = 0.f;
#pragma unroll
    for (int w=0; w<16; w++){
      int slot = (tt*16 + w)*80 + c;
      ssum += smS[slot]; qsum += smQ[slot];
    }
    int blk = swz;                                   // 0..2047 (bijective)
    partial[(size_t)tt*262144 + (size_t)blk*128 + c]      = ssum;
    partial[(size_t)tt*262144 + (size_t)blk*128 + 64 + c] = qsum;
  }
}

// ---------------------------------------------------------------------------
// MFMA 3x3 conv, Cin=Cout=64, bf16 NHWC [8][64][256][64], 2 rows/block (+ReLU)
// BNIN: apply ss-BN to input during staging; STATS: fused output stats partials
// ---------------------------------------------------------------------------
template<bool RELU, bool BNIN, bool STATS>
__global__ __launch_bounds__(256) void conv2_mfma_k(
    const u16* __restrict__ in, const u16* __restrict__ Wt, const float* __restrict__ bias,
    const float* __restrict__ ssin, u16* __restrict__ out, float* __restrict__ partial)
{
  int b = blockIdx.z, y0 = blockIdx.y*2, x0 = blockIdx.x*128;
  int tid = threadIdx.x, lane = tid & 63, wid = tid >> 6;
  int l15 = lane & 15, lhi = lane >> 4;
  __shared__ u16 lds[4*130*64];
  __shared__ float ssm[128];
  if (BNIN){
    if (tid < 128) ssm[tid] = ssin[tid];
    __syncthreads();
  }

  for (int idx = tid; idx < 4160; idx += 256){
    int row = idx >> 3, ch = idx & 7;
    int yy = row / 130, xx = row - yy*130;
    int gy = y0 + yy - 1, gx = x0 + xx - 1;
    us8 w = {0,0,0,0,0,0,0,0};
    if ((unsigned)gy < 64u && (unsigned)gx < 256u){
      us8 v = *(const us8*)(in + ((((size_t)b*64 + gy)*256 + gx)<<6) + ch*8);
      if (BNIN){
#pragma unroll
        for (int e=0; e<8; e++){
          int ci = ch*8 + e;
          w[e] = f2bu(bf2f(v[e])*ssm[ci] + ssm[64+ci]);
        }
      } else w = v;
    }
    *(us8*)(lds + row*64 + ((ch*8) ^ ((xx&7)<<3))) = w;
  }
  __syncthreads();

  f32x4 acc[2][2][4];
#pragma unroll
  for (int nf=0; nf<4; nf++){
    float bb = bias[nf*16 + l15];
#pragma unroll
    for (int ry=0; ry<2; ry++){
      acc[ry][0][nf] = (f32x4){bb,bb,bb,bb};
      acc[ry][1][nf] = (f32x4){bb,bb,bb,bb};
    }
  }
  int xbase = wid*32;
#pragma unroll
  for (int ky=0; ky<3; ky++)
#pragma unroll
    for (int kx=0; kx<3; kx++){
      int t = ky*3 + kx;
      bfx8 bfr[2][4];
#pragma unroll
      for (int ks=0; ks<2; ks++)
#pragma unroll
        for (int nf=0; nf<4; nf++)
          bfr[ks][nf] = ldb8(Wt + ((t*64 + nf*16 + l15)<<6) + ks*32 + lhi*8);
#pragma unroll
      for (int ks=0; ks<2; ks++)
#pragma unroll
        for (int ry=0; ry<2; ry++)
#pragma unroll
          for (int mt=0; mt<2; mt++){
            int xx = xbase + mt*16 + l15 + kx;
            bfx8 a = ldb8(lds + ((ry+ky)*130 + xx)*64 + ((ks*32 + lhi*8) ^ ((xx&7)<<3)));
#pragma unroll
            for (int nf=0; nf<4; nf++)
              acc[ry][mt][nf] = __builtin_amdgcn_mfma_f32_16x16x32_bf16(a, bfr[ks][nf], acc[ry][mt][nf], 0,0,0);
          }
    }
  float s[4] = {0,0,0,0}, qs[4] = {0,0,0,0};
#pragma unroll
  for (int ry=0; ry<2; ry++)
#pragma unroll
    for (int mt=0; mt<2; mt++)
#pragma unroll
      for (int nf=0; nf<4; nf++)
#pragma unroll
        for (int r=0; r<4; r++){
          int x = x0 + xbase + mt*16 + lhi*4 + r;
          float vv = acc[ry][mt][nf][r];
          if (RELU) vv = fmaxf(vv, 0.f);
          u16 ub = f2bu(vv);
          out[((((size_t)b*64 + (y0+ry))*256 + x)<<6) + nf*16 + l15] = ub;
          if (STATS){
            float vb = bf2f(ub);
            s[nf] += vb; qs[nf] += vb*vb;
          }
        }
  if (STATS){
    __syncthreads();
    float* smS = (float*)lds;        // [16][80] stride-80
    float* smQ = smS + 1280;
#pragma unroll
    for (int nf=0; nf<4; nf++){
      smS[(wid*4 + lhi)*80 + nf*16 + l15] = s[nf];
      smQ[(wid*4 + lhi)*80 + nf*16 + l15] = qs[nf];
    }
    __syncthreads();
    if (tid < 64){
      float ssum = 0.f, qsum = 0.f;
#pragma unroll
      for (int w=0; w<16; w++){
        ssum += smS[w*80 + tid]; qsum += smQ[w*80 + tid];
      }
      int blk = (blockIdx.z*32 + blockIdx.y)*2 + blockIdx.x;   // 0..511
      partial[(size_t)blk*128 + tid]      = ssum;
      partial[(size_t)blk*128 + 64 + tid] = qsum;
    }
  }
}

// ---------------------------------------------------------------------------
// MFMA conv on cat [8][64][256][512] -> +bias -> LayerNorm(64), 2 rows/block
// ---------------------------------------------------------------------------
__global__ __launch_bounds__(256) void conv_cat_ln_k(
    const u16* __restrict__ in, const u16* __restrict__ Wt, const float* __restrict__ bias,
    const float* __restrict__ lng, const float* __restrict__ lnb, u16* __restrict__ out)
{
  int b = blockIdx.z, y0 = blockIdx.y*2, x0 = blockIdx.x*128;
  int tid = threadIdx.x, lane = tid & 63, wid = tid >> 6;
  int l15 = lane & 15, lhi = lane >> 4;
  __shared__ u16 lds[4*130*64];

  f32x4 acc[2][2][4];
#pragma unroll
  for (int nf=0; nf<4; nf++){
    float bb = bias[nf*16 + l15];
#pragma unroll
    for (int ry=0; ry<2; ry++){
      acc[ry][0][nf] = (f32x4){bb,bb,bb,bb};
      acc[ry][1][nf] = (f32x4){bb,bb,bb,bb};
    }
  }
  int xbase = wid*32;
  for (int ci0 = 0; ci0 < 512; ci0 += 64){
    __syncthreads();
    for (int idx = tid; idx < 4160; idx += 256){
      int row = idx >> 3, ch = idx & 7;
      int yy = row / 130, xx = row - yy*130;
      int gy = y0 + yy - 1, gx = x0 + xx - 1;
      us8 v = {0,0,0,0,0,0,0,0};
      if ((unsigned)gy < 64u && (unsigned)gx < 256u)
        v = *(const us8*)(in + ((((size_t)b*64 + gy)*256 + gx)<<9) + ci0 + ch*8);
      *(us8*)(lds + row*64 + ((ch*8) ^ ((xx&7)<<3))) = v;
    }
    __syncthreads();
#pragma unroll
    for (int ky=0; ky<3; ky++)
#pragma unroll
      for (int kx=0; kx<3; kx++){
        int t = ky*3 + kx;
        bfx8 bfr[2][4];
#pragma unroll
        for (int ks=0; ks<2; ks++)
#pragma unroll
          for (int nf=0; nf<4; nf++)
            bfr[ks][nf] = ldb8(Wt + ((size_t)(t*64 + nf*16 + l15)<<9) + ci0 + ks*32 + lhi*8);
#pragma unroll
        for (int ks=0; ks<2; ks++)
#pragma unroll
          for (int ry=0; ry<2; ry++)
#pragma unroll
            for (int mt=0; mt<2; mt++){
              int xx = xbase + mt*16 + l15 + kx;
              bfx8 a = ldb8(lds + ((ry+ky)*130 + xx)*64 + ((ks*32 + lhi*8) ^ ((xx&7)<<3)));
#pragma unroll
              for (int nf=0; nf<4; nf++)
                acc[ry][mt][nf] = __builtin_amdgcn_mfma_f32_16x16x32_bf16(a, bfr[ks][nf], acc[ry][mt][nf], 0,0,0);
            }
      }
  }
  float lg[4], lb[4];
#pragma unroll
  for (int nf=0; nf<4; nf++){ lg[nf] = lng[nf*16+l15]; lb[nf] = lnb[nf*16+l15]; }
#pragma unroll
  for (int ry=0; ry<2; ry++)
#pragma unroll
    for (int mt=0; mt<2; mt++)
#pragma unroll
      for (int r=0; r<4; r++){
        float v0 = acc[ry][mt][0][r], v1 = acc[ry][mt][1][r], v2 = acc[ry][mt][2][r], v3 = acc[ry][mt][3][r];
        float s = v0+v1+v2+v3;
        s += __shfl_xor(s,1); s += __shfl_xor(s,2); s += __shfl_xor(s,4); s += __shfl_xor(s,8);
        float m = s * 0.015625f;
        float d0=v0-m, d1=v1-m, d2=v2-m, d3=v3-m;
        float q = d0*d0+d1*d1+d2*d2+d3*d3;
        q += __shfl_xor(q,1); q += __shfl_xor(q,2); q += __shfl_xor(q,4); q += __shfl_xor(q,8);
        float rs = rsqrtf(q*0.015625f + EPS);
        int x = x0 + xbase + mt*16 + lhi*4 + r;
        size_t base = ((((size_t)b*64 + (y0+ry))*256 + x)<<6) + l15;
        out[base]    = f2bu(d0*rs*lg[0] + lb[0]);
        out[base+16] = f2bu(d1*rs*lg[1] + lb[1]);
        out[base+32] = f2bu(d2*rs*lg[2] + lb[2]);
        out[base+48] = f2bu(d3*rs*lg[3] + lb[3]);
      }
}

// grid 3: block tt finalizes tensor tt's 2048 partials (from conv_qkv epilogue)
__global__ __launch_bounds__(256) void finalize3_k(const float* __restrict__ partial,
    const float* __restrict__ gq, const float* __restrict__ bq,
    const float* __restrict__ gk, const float* __restrict__ bk,
    const float* __restrict__ gv, const float* __restrict__ bv,
    float inv_count, float* __restrict__ ssbase)
{
  int tt = blockIdx.x;
  const float* part = partial + (size_t)tt*262144;
  const float* g  = (tt==0)?gq:(tt==1)?gk:gv;
  const float* be = (tt==0)?bq:(tt==1)?bk:bv;
  float* ss = ssbase + tt*128;
  __shared__ float sm[4][128];
  int c = threadIdx.x & 63, qq = threadIdx.x >> 6;
  float s = 0.f, v = 0.f;
  for (int i = qq*512; i < qq*512+512; i++){ s += part[i*128 + c]; v += part[i*128 + 64 + c]; }
  sm[qq][c] = s; sm[qq][64+c] = v;
  __syncthreads();
  if (qq == 0){
    s = sm[0][c]+sm[1][c]+sm[2][c]+sm[3][c];
    v = sm[0][64+c]+sm[1][64+c]+sm[2][64+c]+sm[3][64+c];
    float m = s*inv_count;
    float var = v*inv_count - m*m;
    float sc = g[c]*rsqrtf(var + EPS);
    ss[c] = sc; ss[64+c] = be[c] - m*sc;
  }
}

// finalizes 512 partials (from conv2 fused stats)
__global__ __launch_bounds__(256) void finalize512_k(const float* __restrict__ partial,
                                                     const float* __restrict__ g, const float* __restrict__ beta,
                                                     float inv_count, float* __restrict__ ss)
{
  __shared__ float sm[4][128];
  int c = threadIdx.x & 63, qq = threadIdx.x >> 6;
  float s = 0.f, v = 0.f;
  for (int i = qq*128; i < qq*128+128; i++){ s += partial[i*128 + c]; v += partial[i*128 + 64 + c]; }
  sm[qq][c] = s; sm[qq][64+c] = v;
  __syncthreads();
  if (qq == 0){
    s = sm[0][c]+sm[1][c]+sm[2][c]+sm[3][c];
    v = sm[0][64+c]+sm[1][64+c]+sm[2][64+c]+sm[3][64+c];
    float m = s*inv_count;
    float var = v*inv_count - m*m;
    float sc = g[c]*rsqrtf(var + EPS);
    ss[c] = sc; ss[64+c] = beta[c] - m*sc;
  }
}

// ---------------------------------------------------------------------------
// BN-fused transpose, all 3 tensors in one launch; us8 global r/w
// grid (4, 256, 24): z -> tt = z>>3 (tensor), b = z&7
__global__ __launch_bounds__(256) void bn_tr3_k(const u16* __restrict__ xbase,
                                                const float* __restrict__ ssbase,
                                                u16* __restrict__ xTbase)
{
  int z = blockIdx.z, tt = z >> 3, b = z & 7;
  const u16* x = xbase + (size_t)tt*33554432;
  const float* ss = ssbase + tt*128;
  u16* xT = xTbase + (size_t)tt*33554432;
  int t = blockIdx.y, f0 = blockIdx.x*64;
  __shared__ float sm[64][65];
  int tid = threadIdx.x;
  for (int idx = tid; idx < 512; idx += 256){
    int fi = idx >> 3, cg = idx & 7;
    us8 v = *(const us8*)(x + ((((size_t)b*256 + t)*256 + f0 + fi)<<6) + cg*8);
#pragma unroll
    for (int e=0; e<8; e++){
      int ci = cg*8 + e;
      sm[fi][ci] = bf2f(v[e])*ss[ci] + ss[64+ci];
    }
  }
  __syncthreads();
  for (int idx = tid; idx < 512; idx += 256){
    int ci = idx >> 3, fg = idx & 7;
    us8 o;
#pragma unroll
    for (int e=0; e<8; e++) o[e] = f2bu(sm[fg*8+e][ci]);
    *(us8*)(xT + (((size_t)b*64 + ci)<<16) + t*256 + f0 + fg*8) = o;
  }
}

// ---------------------------------------------------------------------------
// MFMA GEMM: C[bc][i][n] = scale * sum_k A(i,k)*B(n,k), 256x256x256 per bc
template<bool TRA, bool TRB>
__global__ __launch_bounds__(256) void gemm_k(const u16* __restrict__ A, const u16* __restrict__ B,
                                              u16* __restrict__ C, float scale,
                                              int ldC, size_t cBatch, int cOff)
{
  int bc = blockIdx.z;
  const u16* Ab = A + ((size_t)bc<<16);
  const u16* Bb = B + ((size_t)bc<<16);
  u16* Cb = C + (size_t)bc*cBatch + cOff;
  int i0 = blockIdx.y*128, j0 = blockIdx.x*128;
  int tid = threadIdx.x, lane = tid & 63, wid = tid >> 6;
  int l15 = lane & 15, lhi = lane >> 4;
  __shared__ u16 Al[128*64], Bl[128*64];
  f32x4 acc[2][8] = {};

  for (int k0 = 0; k0 < 256; k0 += 64){
    __syncthreads();
    if (!TRA){
      for (int idx = tid; idx < 1024; idx += 256){
        int r = idx >> 3, c8 = idx & 7;
        us8 v = *(const us8*)(Ab + (size_t)(i0+r)*256 + k0 + c8*8);
        *(us8*)(Al + r*64 + ((c8*8) ^ ((r&7)<<3))) = v;
      }
    } else {
      for (int idx = tid; idx < 1024; idx += 256){
        int kr = idx >> 4, c8 = idx & 15;
        us8 v = *(const us8*)(Ab + (size_t)(k0+kr)*256 + i0 + c8*8);
#pragma unroll
        for (int e=0; e<8; e++){
          int i = c8*8 + e;
          Al[i*64 + (kr ^ ((i&7)<<3))] = v[e];
        }
      }
    }
    if (!TRB){
      for (int idx = tid; idx < 1024; idx += 256){
        int r = idx >> 3, c8 = idx & 7;
        us8 v = *(const us8*)(Bb + (size_t)(j0+r)*256 + k0 + c8*8);
        *(us8*)(Bl + r*64 + ((c8*8) ^ ((r&7)<<3))) = v;
      }
    } else {
      for (int idx = tid; idx < 1024; idx += 256){
        int kr = idx >> 4, c8 = idx & 15;
        us8 v = *(const us8*)(Bb + (size_t)(k0+kr)*256 + j0 + c8*8);
#pragma unroll
        for (int e=0; e<8; e++){
          int j = c8*8 + e;
          Bl[j*64 + (kr ^ ((j&7)<<3))] = v[e];
        }
      }
    }
    __syncthreads();
    int wrow = wid*32;
#pragma unroll
    for (int ks=0; ks<2; ks++){
      bfx8 bfr[8];
#pragma unroll
      for (int nf=0; nf<8; nf++)
        bfr[nf] = ldb8(Bl + (nf*16+l15)*64 + ((ks*32 + lhi*8) ^ ((l15&7)<<3)));
#pragma unroll
      for (int mt=0; mt<2; mt++){
        int r = wrow + mt*16 + l15;
        bfx8 a = ldb8(Al + r*64 + ((ks*32 + lhi*8) ^ ((r&7)<<3)));
#pragma unroll
        for (int nf=0; nf<8; nf++)
          acc[mt][nf] = __builtin_amdgcn_mfma_f32_16x16x32_bf16(a, bfr[nf], acc[mt][nf], 0,0,0);
      }
    }
  }
#pragma unroll
  for (int mt=0; mt<2; mt++)
#pragma unroll
    for (int nf=0; nf<8; nf++)
#pragma unroll
      for (int r=0; r<4; r++){
        int i = i0 + wid*32 + mt*16 + lhi*4 + r;
        int j = j0 + nf*16 + l15;
        Cb[(size_t)i*ldC + j] = f2bu(acc[mt][nf][r]*scale);
      }
}

// softmax over rows of 256 (one wave per row), in-place
__global__ __launch_bounds__(256) void softmax_k(u16* __restrict__ P)
{
  size_t row = (size_t)blockIdx.x*4 + (threadIdx.x >> 6);
  int lane = threadIdx.x & 63;
  u16* p = P + row*256 + lane*4;
  us4 u = *(us4*)p;
  float v[4];
#pragma unroll
  for (int e=0; e<4; e++) v[e] = bf2f(u[e]);
  float m = fmaxf(fmaxf(v[0],v[1]), fmaxf(v[2],v[3]));
  for (int off=1; off<64; off<<=1) m = fmaxf(m, __shfl_xor(m, off));
  float s = 0.f;
#pragma unroll
  for (int e=0; e<4; e++){ v[e] = __expf(v[e]-m); s += v[e]; }
  for (int off=1; off<64; off<<=1) s += __shfl_xor(s, off);
  float inv = 1.f/s;
  us4 o;
#pragma unroll
  for (int e=0; e<4; e++) o[e] = f2bu(v[e]*inv);
  *(us4*)p = o;
}

__global__ __launch_bounds__(256) void apply_bn_f_k(const u16* __restrict__ x, const float* __restrict__ ss,
                                                    float* __restrict__ out, int n4)
{
  int i = blockIdx.x*256 + threadIdx.x;
  if (i < n4){
    int c0 = (i & 15)*4;
    us4 u = ((const us4*)x)[i];
    float4 o;
    o.x = bf2f(u[0])*ss[c0]   + ss[64+c0];
    o.y = bf2f(u[1])*ss[c0+1] + ss[64+c0+1];
    o.z = bf2f(u[2])*ss[c0+2] + ss[64+c0+2];
    o.w = bf2f(u[3])*ss[c0+3] + ss[64+c0+3];
    ((float4*)out)[i] = o;
  }
}

// ---------------------------------------------------------------------------
extern "C" void kernel_launch(void* const* d_in, const int* in_sizes, int n_in,
                              void* d_out, int out_size, void* d_ws, size_t ws_size,
                              hipStream_t stream)
{
  const float* in    = (const float*)d_in[0];
  const float* wq    = (const float*)d_in[1];  const float* bq    = (const float*)d_in[2];
  const float* wk    = (const float*)d_in[3];  const float* bk    = (const float*)d_in[4];
  const float* wv    = (const float*)d_in[5];  const float* bv    = (const float*)d_in[6];
  const float* gq    = (const float*)d_in[7];  const float* betaq = (const float*)d_in[8];
  const float* gk    = (const float*)d_in[9];  const float* betak = (const float*)d_in[10];
  const float* gv    = (const float*)d_in[11]; const float* betav = (const float*)d_in[12];
  const float* wc    = (const float*)d_in[13]; const float* bcv   = (const float*)d_in[14];
  const float* lng   = (const float*)d_in[15]; const float* lnb   = (const float*)d_in[16];
  const float* w1    = (const float*)d_in[17]; const float* b1    = (const float*)d_in[18];
  const float* g1    = (const float*)d_in[19]; const float* beta1 = (const float*)d_in[20];
  const float* w2    = (const float*)d_in[21]; const float* b2    = (const float*)d_in[22];
  const float* g2    = (const float*)d_in[23]; const float* beta2 = (const float*)d_in[24];
  float* out = (float*)d_out;

  char* ws = (char*)d_ws;
  const size_t MB = 1ull<<20;
  // Layout (reuse only after last read; input never copied):
  //   0..64    qraw -> P1
  //   64..128  kraw -> P2        (P1,P2 contiguous: single softmax launch)
  //   128..192 vraw -> y0(128..144), f1(144..160), rr(160..176)
  //   192..256 qT  --\ cat = 192..320
  //   256..320 kT  --/
  //   320..384 vT   (partial @352, 3MB: conv_qkv writes -> finalize3 reads,
  //                  all before bn_tr3 writes vT; conv2 stats rewrite it after
  //                  vT is dead)
  //   384+     ss (5x128) + prepped weights (~1.2MB)
  u16* qraw = (u16*)(ws);
  u16* kraw = (u16*)(ws + 64*MB);
  u16* vraw = (u16*)(ws + 128*MB);
  u16* qT   = (u16*)(ws + 192*MB);
  u16* kT   = (u16*)(ws + 256*MB);
  u16* vT   = (u16*)(ws + 320*MB);
  u16* P1   = qraw;
  u16* P2   = kraw;
  u16* cat  = qT;
  u16* y0   = (u16*)(ws + 128*MB);
  u16* f1   = (u16*)(ws + 144*MB);
  u16* rr   = (u16*)(ws + 160*MB);
  float* partial = (float*)(ws + 352*MB);            // 3MB (3 x 2048 x 128)
  float* ssq = (float*)(ws + 384*MB);                // ssq,ssk,ssv contiguous
  float* ss1 = ssq + 384;  float* ss2 = ssq + 512;
  u16* wqT = (u16*)(ws + 384*MB + 4096);             // 5 x 36864 contiguous + wcT
  u16* wkT = wqT + 36864; u16* wvT = wkT + 36864;
  u16* w1T = wvT + 36864; u16* w2T = w1T + 36864;
  u16* wcT = w2T + 36864;                            // 294912 elems

  dim3 blk(256);
  dim3 blk768(768);

  prepw5_k<<<dim3(144,5), blk, 0, stream>>>(wq, wk, wv, w1, w2, wqT);
  prepw_k<<<1152, blk, 0, stream>>>(wc, wcT, 512);

  const float invN1 = 1.f/524288.f;
  conv_qkv_f32_k<<<dim3(2,128,8), blk768, 0, stream>>>(in, wqT,wkT,wvT, bq,bk,bv,
                                                       qraw,kraw,vraw, partial);
  finalize3_k<<<3, blk, 0, stream>>>(partial, gq,betaq, gk,betak, gv,betav, invN1, ssq);
  bn_tr3_k<<<dim3(4,256,24), blk, 0, stream>>>(qraw, ssq, qT);

  // scores: time (row-major both), freq (k-major both)
  gemm_k<false,false><<<dim3(2,2,512), blk, 0, stream>>>(qT, kT, P1, 0.0625f, 256, 65536, 0);
  gemm_k<true ,true ><<<dim3(2,2,512), blk, 0, stream>>>(qT, kT, P2, 0.0625f, 256, 65536, 0);
  softmax_k<<<65536, blk, 0, stream>>>(P1);   // P1 and P2 are contiguous
  // AV: time C[t][f] = sum_j P1[t][j] vT[j][f] -> TRB=true
  //     freq C[f][t] = sum_j P2[f][j] vT[t][j] -> TRB=false
  gemm_k<false,true ><<<dim3(2,2,512), blk, 0, stream>>>(P1, vT, cat, 1.f, 512, 131072, 0);
  gemm_k<false,false><<<dim3(2,2,512), blk, 0, stream>>>(P2, vT, cat, 1.f, 512, 131072, 256);

  conv_cat_ln_k<<<dim3(2,32,8), blk, 0, stream>>>(cat, wcT, bcv, lng, lnb, y0);

  const float invN2 = 1.f/131072.f;
  conv2_mfma_k<true,false,true><<<dim3(2,32,8), blk, 0, stream>>>(y0, w1T, b1, ssq, rr, partial);
  finalize512_k<<<1, blk, 0, stream>>>(partial, g1, beta1, invN2, ss1);

  conv2_mfma_k<true,true,true><<<dim3(2,32,8), blk, 0, stream>>>(rr, w2T, b2, ss1, f1, partial);
  finalize512_k<<<1, blk, 0, stream>>>(partial, g2, beta2, invN2, ss2);
  apply_bn_f_k<<<8192, blk, 0, stream>>>(f1, ss2, out, 2097152);
}

// Round 20
// 1096.693 us; speedup vs baseline: 1.0615x; 1.0555x over previous
//
#include <hip/hip_runtime.h>
#include <hip/hip_bf16.h>

typedef unsigned short u16;
typedef u16 us8 __attribute__((ext_vector_type(8)));
typedef u16 us4 __attribute__((ext_vector_type(4)));
typedef __bf16 bfx8 __attribute__((ext_vector_type(8)));
typedef float f32x4 __attribute__((ext_vector_type(4)));

#define EPS 1e-3f

__device__ __forceinline__ float bf2f(u16 u){ unsigned x = ((unsigned)u)<<16; return __builtin_bit_cast(float, x); }
__device__ __forceinline__ u16 f2bu(float f){ __hip_bfloat16 h = __float2bfloat16(f); return __builtin_bit_cast(u16, h); }
__device__ __forceinline__ bfx8 ldb8(const u16* p){ return __builtin_bit_cast(bfx8, *(const us8*)p); }

// direct global->LDS DMA, 16B per lane; LDS dest = wave-uniform base + lane*16B
typedef const __attribute__((address_space(1))) unsigned int cguint;
typedef __attribute__((address_space(3))) unsigned int lduint;
__device__ __forceinline__ void gload16(const u16* g, u16* l){
  __builtin_amdgcn_global_load_lds((cguint*)g, (lduint*)l, 16, 0, 0);
}

// five [9][64][64] f32 weight sets -> [9][64][64] bf16 (co-major), one launch
__global__ __launch_bounds__(256) void prepw5_k(
    const float* __restrict__ w0, const float* __restrict__ w1, const float* __restrict__ w2,
    const float* __restrict__ w3, const float* __restrict__ w4, u16* __restrict__ dst)
{
  int which = blockIdx.y;
  const float* src = which==0?w0:which==1?w1:which==2?w2:which==3?w3:w4;
  u16* d = dst + (size_t)which*36864;
  int idx = blockIdx.x*256 + threadIdx.x;
  if (idx < 36864){
    int ci = idx & 63; int rest = idx >> 6; int co = rest & 63; int t = rest >> 6;
    d[idx] = f2bu(src[((size_t)t*64 + ci)*64 + co]);
  }
}

// weights [9][CI][64] f32 -> [9][64][CI] bf16 (for wc, CI=512)
__global__ __launch_bounds__(256) void prepw_k(const float* __restrict__ src, u16* __restrict__ dst, int CI)
{
  int total = 9*CI*64;
  int idx = blockIdx.x*256 + threadIdx.x;
  if (idx < total){
    int ci = idx % CI; int rest = idx / CI; int co = rest & 63; int t = rest >> 6;
    dst[idx] = f2bu(src[((size_t)t*CI + ci)*64 + co]);
  }
}

// ---------------------------------------------------------------------------
// FUSED q/k/v MFMA 3x3 conv + per-channel stats partials, f32 input NHWC
// block 768 = 3 tensor-groups x 4 waves; tile = 2 rows x 128 x
// XCD-aware block swizzle; outputs staged through LDS -> coalesced 128B stores
// ---------------------------------------------------------------------------
__global__ __launch_bounds__(768) void conv_qkv_f32_k(
    const float* __restrict__ in,
    const u16* __restrict__ WtQ, const u16* __restrict__ WtK, const u16* __restrict__ WtV,
    const float* __restrict__ bq, const float* __restrict__ bk, const float* __restrict__ bv,
    u16* __restrict__ qo, u16* __restrict__ ko, u16* __restrict__ vo,
    float* __restrict__ partial)
{
  // flatten launch grid (2,128,8) -> bijective XCD chunk swizzle (nwg=2048)
  int lin = (blockIdx.z*128 + blockIdx.y)*2 + blockIdx.x;
  int swz = (lin & 7)*256 + (lin >> 3);
  int bx = swz & 1, by = (swz >> 1) & 127, bz = swz >> 8;
  int b = bz, y0 = by*2, x0 = bx*128;
  int tid = threadIdx.x, lane = tid & 63, wid = tid >> 6;   // wid 0..11
  int g3 = wid >> 2, wid4 = wid & 3;
  int l15 = lane & 15, lhi = lane >> 4;
  __shared__ u16 lds[4*130*64];

  for (int idx = tid; idx < 8320; idx += 768){
    int row = idx >> 4, c4 = idx & 15;
    int yy = row / 130, xx = row - yy*130;
    int gy = y0 + yy - 1, gx = x0 + xx - 1;
    us4 v = {0,0,0,0};
    if ((unsigned)gy < 256u && (unsigned)gx < 256u){
      float4 f = *(const float4*)(in + ((((size_t)b*256 + gy)*256 + gx)<<6) + c4*4);
      v[0] = f2bu(f.x); v[1] = f2bu(f.y); v[2] = f2bu(f.z); v[3] = f2bu(f.w);
    }
    *(us4*)(lds + row*64 + ((c4*4) ^ ((xx&7)<<3))) = v;
  }
  __syncthreads();

  const u16*  Wt   = (g3==0) ? WtQ : (g3==1) ? WtK : WtV;
  const float* bias = (g3==0) ? bq  : (g3==1) ? bk  : bv;

  f32x4 acc[2][2][4];
#pragma unroll
  for (int nf=0; nf<4; nf++){
    float bb = bias[nf*16 + l15];
#pragma unroll
    for (int ry=0; ry<2; ry++){
      acc[ry][0][nf] = (f32x4){bb,bb,bb,bb};
      acc[ry][1][nf] = (f32x4){bb,bb,bb,bb};
    }
  }
  int xbase = wid4*32;
#pragma unroll
  for (int ky=0; ky<3; ky++)
#pragma unroll
    for (int kx=0; kx<3; kx++){
      int t = ky*3 + kx;
      bfx8 bfr[2][4];
#pragma unroll
      for (int ks=0; ks<2; ks++)
#pragma unroll
        for (int nf=0; nf<4; nf++)
          bfr[ks][nf] = ldb8(Wt + ((t*64 + nf*16 + l15)<<6) + ks*32 + lhi*8);
#pragma unroll
      for (int ks=0; ks<2; ks++)
#pragma unroll
        for (int ry=0; ry<2; ry++)
#pragma unroll
          for (int mt=0; mt<2; mt++){
            int xx = xbase + mt*16 + l15 + kx;
            bfx8 a = ldb8(lds + ((ry+ky)*130 + xx)*64 + ((ks*32 + lhi*8) ^ ((xx&7)<<3)));
#pragma unroll
            for (int nf=0; nf<4; nf++)
              acc[ry][mt][nf] = __builtin_amdgcn_mfma_f32_16x16x32_bf16(a, bfr[ks][nf], acc[ry][mt][nf], 0,0,0);
          }
    }
  // epilogue: stage outputs in LDS ([3][128][72] u16), coalesced 128B stores
  float s[4] = {0,0,0,0}, qs[4] = {0,0,0,0};
#pragma unroll
  for (int ry=0; ry<2; ry++){
    __syncthreads();
#pragma unroll
    for (int mt=0; mt<2; mt++)
#pragma unroll
      for (int nf=0; nf<4; nf++)
#pragma unroll
        for (int r=0; r<4; r++){
          int xloc = xbase + mt*16 + lhi*4 + r;
          u16 ub = f2bu(acc[ry][mt][nf][r]);
          lds[(g3*128 + xloc)*72 + nf*16 + l15] = ub;
          float vv = bf2f(ub);
          s[nf] += vv; qs[nf] += vv*vv;
        }
    __syncthreads();
    for (int idx = tid; idx < 3072; idx += 768){
      int row = idx >> 3, p8 = idx & 7;           // row = g*128 + xloc
      int g = row >> 7, xloc = row & 127;
      us8 v = *(const us8*)(lds + row*72 + p8*8);
      u16* op = (g==0) ? qo : (g==1) ? ko : vo;
      *(us8*)(op + ((((size_t)b*256 + (y0+ry))*256 + (x0+xloc))<<6) + p8*8) = v;
    }
  }
  __syncthreads();
  float* smS = (float*)lds;          // [48][80] stride-80
  float* smQ = smS + 3840;
#pragma unroll
  for (int nf=0; nf<4; nf++){
    smS[(wid*4 + lhi)*80 + nf*16 + l15] = s[nf];
    smQ[(wid*4 + lhi)*80 + nf*16 + l15] = qs[nf];
  }
  __syncthreads();
  if (tid < 192){
    int tt = tid >> 6, c = tid & 63;
    float ssum = 0.f, qsum = 0.f;
#pragma unroll
    for (int w=0; w<16; w++){
      int slot = (tt*16 + w)*80 + c;
      ssum += smS[slot]; qsum += smQ[slot];
    }
    int blk = swz;                                   // 0..2047 (bijective)
    partial[(size_t)tt*262144 + (size_t)blk*128 + c]      = ssum;
    partial[(size_t)tt*262144 + (size_t)blk*128 + 64 + c] = qsum;
  }
}

// ---------------------------------------------------------------------------
// MFMA 3x3 conv, Cin=Cout=64, bf16 NHWC [8][64][256][64], 2 rows/block (+ReLU)
// BNIN: apply ss-BN to input during staging; STATS: fused output stats partials
// ---------------------------------------------------------------------------
template<bool RELU, bool BNIN, bool STATS>
__global__ __launch_bounds__(256) void conv2_mfma_k(
    const u16* __restrict__ in, const u16* __restrict__ Wt, const float* __restrict__ bias,
    const float* __restrict__ ssin, u16* __restrict__ out, float* __restrict__ partial)
{
  int b = blockIdx.z, y0 = blockIdx.y*2, x0 = blockIdx.x*128;
  int tid = threadIdx.x, lane = tid & 63, wid = tid >> 6;
  int l15 = lane & 15, lhi = lane >> 4;
  __shared__ u16 lds[4*130*64];
  __shared__ float ssm[128];
  if (BNIN){
    if (tid < 128) ssm[tid] = ssin[tid];
    __syncthreads();
  }

  for (int idx = tid; idx < 4160; idx += 256){
    int row = idx >> 3, ch = idx & 7;
    int yy = row / 130, xx = row - yy*130;
    int gy = y0 + yy - 1, gx = x0 + xx - 1;
    us8 w = {0,0,0,0,0,0,0,0};
    if ((unsigned)gy < 64u && (unsigned)gx < 256u){
      us8 v = *(const us8*)(in + ((((size_t)b*64 + gy)*256 + gx)<<6) + ch*8);
      if (BNIN){
#pragma unroll
        for (int e=0; e<8; e++){
          int ci = ch*8 + e;
          w[e] = f2bu(bf2f(v[e])*ssm[ci] + ssm[64+ci]);
        }
      } else w = v;
    }
    *(us8*)(lds + row*64 + ((ch*8) ^ ((xx&7)<<3))) = w;
  }
  __syncthreads();

  f32x4 acc[2][2][4];
#pragma unroll
  for (int nf=0; nf<4; nf++){
    float bb = bias[nf*16 + l15];
#pragma unroll
    for (int ry=0; ry<2; ry++){
      acc[ry][0][nf] = (f32x4){bb,bb,bb,bb};
      acc[ry][1][nf] = (f32x4){bb,bb,bb,bb};
    }
  }
  int xbase = wid*32;
#pragma unroll
  for (int ky=0; ky<3; ky++)
#pragma unroll
    for (int kx=0; kx<3; kx++){
      int t = ky*3 + kx;
      bfx8 bfr[2][4];
#pragma unroll
      for (int ks=0; ks<2; ks++)
#pragma unroll
        for (int nf=0; nf<4; nf++)
          bfr[ks][nf] = ldb8(Wt + ((t*64 + nf*16 + l15)<<6) + ks*32 + lhi*8);
#pragma unroll
      for (int ks=0; ks<2; ks++)
#pragma unroll
        for (int ry=0; ry<2; ry++)
#pragma unroll
          for (int mt=0; mt<2; mt++){
            int xx = xbase + mt*16 + l15 + kx;
            bfx8 a = ldb8(lds + ((ry+ky)*130 + xx)*64 + ((ks*32 + lhi*8) ^ ((xx&7)<<3)));
#pragma unroll
            for (int nf=0; nf<4; nf++)
              acc[ry][mt][nf] = __builtin_amdgcn_mfma_f32_16x16x32_bf16(a, bfr[ks][nf], acc[ry][mt][nf], 0,0,0);
          }
    }
  float s[4] = {0,0,0,0}, qs[4] = {0,0,0,0};
#pragma unroll
  for (int ry=0; ry<2; ry++)
#pragma unroll
    for (int mt=0; mt<2; mt++)
#pragma unroll
      for (int nf=0; nf<4; nf++)
#pragma unroll
        for (int r=0; r<4; r++){
          int x = x0 + xbase + mt*16 + lhi*4 + r;
          float vv = acc[ry][mt][nf][r];
          if (RELU) vv = fmaxf(vv, 0.f);
          u16 ub = f2bu(vv);
          out[((((size_t)b*64 + (y0+ry))*256 + x)<<6) + nf*16 + l15] = ub;
          if (STATS){
            float vb = bf2f(ub);
            s[nf] += vb; qs[nf] += vb*vb;
          }
        }
  if (STATS){
    __syncthreads();
    float* smS = (float*)lds;        // [16][80] stride-80
    float* smQ = smS + 1280;
#pragma unroll
    for (int nf=0; nf<4; nf++){
      smS[(wid*4 + lhi)*80 + nf*16 + l15] = s[nf];
      smQ[(wid*4 + lhi)*80 + nf*16 + l15] = qs[nf];
    }
    __syncthreads();
    if (tid < 64){
      float ssum = 0.f, qsum = 0.f;
#pragma unroll
      for (int w=0; w<16; w++){
        ssum += smS[w*80 + tid]; qsum += smQ[w*80 + tid];
      }
      int blk = (blockIdx.z*32 + blockIdx.y)*2 + blockIdx.x;   // 0..511
      partial[(size_t)blk*128 + tid]      = ssum;
      partial[(size_t)blk*128 + 64 + tid] = qsum;
    }
  }
}

// ---------------------------------------------------------------------------
// MFMA conv on cat [8][64][256][512] -> +bias -> LayerNorm(64), 2 rows/block
// ---------------------------------------------------------------------------
__global__ __launch_bounds__(256) void conv_cat_ln_k(
    const u16* __restrict__ in, const u16* __restrict__ Wt, const float* __restrict__ bias,
    const float* __restrict__ lng, const float* __restrict__ lnb, u16* __restrict__ out)
{
  int b = blockIdx.z, y0 = blockIdx.y*2, x0 = blockIdx.x*128;
  int tid = threadIdx.x, lane = tid & 63, wid = tid >> 6;
  int l15 = lane & 15, lhi = lane >> 4;
  __shared__ u16 lds[4*130*64];

  f32x4 acc[2][2][4];
#pragma unroll
  for (int nf=0; nf<4; nf++){
    float bb = bias[nf*16 + l15];
#pragma unroll
    for (int ry=0; ry<2; ry++){
      acc[ry][0][nf] = (f32x4){bb,bb,bb,bb};
      acc[ry][1][nf] = (f32x4){bb,bb,bb,bb};
    }
  }
  int xbase = wid*32;
  for (int ci0 = 0; ci0 < 512; ci0 += 64){
    __syncthreads();
    for (int idx = tid; idx < 4160; idx += 256){
      int row = idx >> 3, ch = idx & 7;
      int yy = row / 130, xx = row - yy*130;
      int gy = y0 + yy - 1, gx = x0 + xx - 1;
      us8 v = {0,0,0,0,0,0,0,0};
      if ((unsigned)gy < 64u && (unsigned)gx < 256u)
        v = *(const us8*)(in + ((((size_t)b*64 + gy)*256 + gx)<<9) + ci0 + ch*8);
      *(us8*)(lds + row*64 + ((ch*8) ^ ((xx&7)<<3))) = v;
    }
    __syncthreads();
#pragma unroll
    for (int ky=0; ky<3; ky++)
#pragma unroll
      for (int kx=0; kx<3; kx++){
        int t = ky*3 + kx;
        bfx8 bfr[2][4];
#pragma unroll
        for (int ks=0; ks<2; ks++)
#pragma unroll
          for (int nf=0; nf<4; nf++)
            bfr[ks][nf] = ldb8(Wt + ((size_t)(t*64 + nf*16 + l15)<<9) + ci0 + ks*32 + lhi*8);
#pragma unroll
        for (int ks=0; ks<2; ks++)
#pragma unroll
          for (int ry=0; ry<2; ry++)
#pragma unroll
            for (int mt=0; mt<2; mt++){
              int xx = xbase + mt*16 + l15 + kx;
              bfx8 a = ldb8(lds + ((ry+ky)*130 + xx)*64 + ((ks*32 + lhi*8) ^ ((xx&7)<<3)));
#pragma unroll
              for (int nf=0; nf<4; nf++)
                acc[ry][mt][nf] = __builtin_amdgcn_mfma_f32_16x16x32_bf16(a, bfr[ks][nf], acc[ry][mt][nf], 0,0,0);
            }
      }
  }
  float lg[4], lb[4];
#pragma unroll
  for (int nf=0; nf<4; nf++){ lg[nf] = lng[nf*16+l15]; lb[nf] = lnb[nf*16+l15]; }
#pragma unroll
  for (int ry=0; ry<2; ry++)
#pragma unroll
    for (int mt=0; mt<2; mt++)
#pragma unroll
      for (int r=0; r<4; r++){
        float v0 = acc[ry][mt][0][r], v1 = acc[ry][mt][1][r], v2 = acc[ry][mt][2][r], v3 = acc[ry][mt][3][r];
        float s = v0+v1+v2+v3;
        s += __shfl_xor(s,1); s += __shfl_xor(s,2); s += __shfl_xor(s,4); s += __shfl_xor(s,8);
        float m = s * 0.015625f;
        float d0=v0-m, d1=v1-m, d2=v2-m, d3=v3-m;
        float q = d0*d0+d1*d1+d2*d2+d3*d3;
        q += __shfl_xor(q,1); q += __shfl_xor(q,2); q += __shfl_xor(q,4); q += __shfl_xor(q,8);
        float rs = rsqrtf(q*0.015625f + EPS);
        int x = x0 + xbase + mt*16 + lhi*4 + r;
        size_t base = ((((size_t)b*64 + (y0+ry))*256 + x)<<6) + l15;
        out[base]    = f2bu(d0*rs*lg[0] + lb[0]);
        out[base+16] = f2bu(d1*rs*lg[1] + lb[1]);
        out[base+32] = f2bu(d2*rs*lg[2] + lb[2]);
        out[base+48] = f2bu(d3*rs*lg[3] + lb[3]);
      }
}

// grid 3: block tt finalizes tensor tt's 2048 partials (from conv_qkv epilogue)
__global__ __launch_bounds__(256) void finalize3_k(const float* __restrict__ partial,
    const float* __restrict__ gq, const float* __restrict__ bq,
    const float* __restrict__ gk, const float* __restrict__ bk,
    const float* __restrict__ gv, const float* __restrict__ bv,
    float inv_count, float* __restrict__ ssbase)
{
  int tt = blockIdx.x;
  const float* part = partial + (size_t)tt*262144;
  const float* g  = (tt==0)?gq:(tt==1)?gk:gv;
  const float* be = (tt==0)?bq:(tt==1)?bk:bv;
  float* ss = ssbase + tt*128;
  __shared__ float sm[4][128];
  int c = threadIdx.x & 63, qq = threadIdx.x >> 6;
  float s = 0.f, v = 0.f;
  for (int i = qq*512; i < qq*512+512; i++){ s += part[i*128 + c]; v += part[i*128 + 64 + c]; }
  sm[qq][c] = s; sm[qq][64+c] = v;
  __syncthreads();
  if (qq == 0){
    s = sm[0][c]+sm[1][c]+sm[2][c]+sm[3][c];
    v = sm[0][64+c]+sm[1][64+c]+sm[2][64+c]+sm[3][64+c];
    float m = s*inv_count;
    float var = v*inv_count - m*m;
    float sc = g[c]*rsqrtf(var + EPS);
    ss[c] = sc; ss[64+c] = be[c] - m*sc;
  }
}

// finalizes 512 partials (from conv2 fused stats)
__global__ __launch_bounds__(256) void finalize512_k(const float* __restrict__ partial,
                                                     const float* __restrict__ g, const float* __restrict__ beta,
                                                     float inv_count, float* __restrict__ ss)
{
  __shared__ float sm[4][128];
  int c = threadIdx.x & 63, qq = threadIdx.x >> 6;
  float s = 0.f, v = 0.f;
  for (int i = qq*128; i < qq*128+128; i++){ s += partial[i*128 + c]; v += partial[i*128 + 64 + c]; }
  sm[qq][c] = s; sm[qq][64+c] = v;
  __syncthreads();
  if (qq == 0){
    s = sm[0][c]+sm[1][c]+sm[2][c]+sm[3][c];
    v = sm[0][64+c]+sm[1][64+c]+sm[2][64+c]+sm[3][64+c];
    float m = s*inv_count;
    float var = v*inv_count - m*m;
    float sc = g[c]*rsqrtf(var + EPS);
    ss[c] = sc; ss[64+c] = beta[c] - m*sc;
  }
}

// ---------------------------------------------------------------------------
// BN-fused transpose, all 3 tensors in one launch; us8 global r/w
// grid (4, 256, 24): z -> tt = z>>3 (tensor), b = z&7
__global__ __launch_bounds__(256) void bn_tr3_k(const u16* __restrict__ xbase,
                                                const float* __restrict__ ssbase,
                                                u16* __restrict__ xTbase)
{
  int z = blockIdx.z, tt = z >> 3, b = z & 7;
  const u16* x = xbase + (size_t)tt*33554432;
  const float* ss = ssbase + tt*128;
  u16* xT = xTbase + (size_t)tt*33554432;
  int t = blockIdx.y, f0 = blockIdx.x*64;
  __shared__ float sm[64][65];
  int tid = threadIdx.x;
  for (int idx = tid; idx < 512; idx += 256){
    int fi = idx >> 3, cg = idx & 7;
    us8 v = *(const us8*)(x + ((((size_t)b*256 + t)*256 + f0 + fi)<<6) + cg*8);
#pragma unroll
    for (int e=0; e<8; e++){
      int ci = cg*8 + e;
      sm[fi][ci] = bf2f(v[e])*ss[ci] + ss[64+ci];
    }
  }
  __syncthreads();
  for (int idx = tid; idx < 512; idx += 256){
    int ci = idx >> 3, fg = idx & 7;
    us8 o;
#pragma unroll
    for (int e=0; e<8; e++) o[e] = f2bu(sm[fg*8+e][ci]);
    *(us8*)(xT + (((size_t)b*64 + ci)<<16) + t*256 + f0 + fg*8) = o;
  }
}

// ---------------------------------------------------------------------------
// MFMA GEMM: C[bc][i][n] = scale * sum_k A(i,k)*B(n,k), 256x256x256 per bc
// non-transposed operand staging via global_load_lds (linear LDS dest,
// swizzle applied to the per-lane GLOBAL source; read side unchanged)
template<bool TRA, bool TRB>
__global__ __launch_bounds__(256) void gemm_k(const u16* __restrict__ A, const u16* __restrict__ B,
                                              u16* __restrict__ C, float scale,
                                              int ldC, size_t cBatch, int cOff)
{
  int bc = blockIdx.z;
  const u16* Ab = A + ((size_t)bc<<16);
  const u16* Bb = B + ((size_t)bc<<16);
  u16* Cb = C + (size_t)bc*cBatch + cOff;
  int i0 = blockIdx.y*128, j0 = blockIdx.x*128;
  int tid = threadIdx.x, lane = tid & 63, wid = tid >> 6;
  int l15 = lane & 15, lhi = lane >> 4;
  __shared__ u16 Al[128*64], Bl[128*64];
  f32x4 acc[2][8] = {};

  int r_off = lane >> 3, c8g = lane & 7;    // lane -> (row-in-8, colgroup)

  for (int k0 = 0; k0 < 256; k0 += 64){
    __syncthreads();
    if (!TRA){
#pragma unroll
      for (int it = 0; it < 4; it++){
        int rb = it*32 + wid*8;
        int r  = rb + r_off;
        gload16(Ab + (size_t)(i0+r)*256 + k0 + 8*(c8g ^ (r&7)), Al + rb*64);
      }
    } else {
      for (int idx = tid; idx < 1024; idx += 256){
        int kr = idx >> 4, c8 = idx & 15;
        us8 v = *(const us8*)(Ab + (size_t)(k0+kr)*256 + i0 + c8*8);
#pragma unroll
        for (int e=0; e<8; e++){
          int i = c8*8 + e;
          Al[i*64 + (kr ^ ((i&7)<<3))] = v[e];
        }
      }
    }
    if (!TRB){
#pragma unroll
      for (int it = 0; it < 4; it++){
        int rb = it*32 + wid*8;
        int r  = rb + r_off;
        gload16(Bb + (size_t)(j0+r)*256 + k0 + 8*(c8g ^ (r&7)), Bl + rb*64);
      }
    } else {
      for (int idx = tid; idx < 1024; idx += 256){
        int kr = idx >> 4, c8 = idx & 15;
        us8 v = *(const us8*)(Bb + (size_t)(k0+kr)*256 + j0 + c8*8);
#pragma unroll
        for (int e=0; e<8; e++){
          int j = c8*8 + e;
          Bl[j*64 + (kr ^ ((j&7)<<3))] = v[e];
        }
      }
    }
    __syncthreads();
    int wrow = wid*32;
#pragma unroll
    for (int ks=0; ks<2; ks++){
      bfx8 bfr[8];
#pragma unroll
      for (int nf=0; nf<8; nf++)
        bfr[nf] = ldb8(Bl + (nf*16+l15)*64 + ((ks*32 + lhi*8) ^ ((l15&7)<<3)));
#pragma unroll
      for (int mt=0; mt<2; mt++){
        int r = wrow + mt*16 + l15;
        bfx8 a = ldb8(Al + r*64 + ((ks*32 + lhi*8) ^ ((r&7)<<3)));
#pragma unroll
        for (int nf=0; nf<8; nf++)
          acc[mt][nf] = __builtin_amdgcn_mfma_f32_16x16x32_bf16(a, bfr[nf], acc[mt][nf], 0,0,0);
      }
    }
  }
#pragma unroll
  for (int mt=0; mt<2; mt++)
#pragma unroll
    for (int nf=0; nf<8; nf++)
#pragma unroll
      for (int r=0; r<4; r++){
        int i = i0 + wid*32 + mt*16 + lhi*4 + r;
        int j = j0 + nf*16 + l15;
        Cb[(size_t)i*ldC + j] = f2bu(acc[mt][nf][r]*scale);
      }
}

// softmax over rows of 256 (one wave per row), in-place
__global__ __launch_bounds__(256) void softmax_k(u16* __restrict__ P)
{
  size_t row = (size_t)blockIdx.x*4 + (threadIdx.x >> 6);
  int lane = threadIdx.x & 63;
  u16* p = P + row*256 + lane*4;
  us4 u = *(us4*)p;
  float v[4];
#pragma unroll
  for (int e=0; e<4; e++) v[e] = bf2f(u[e]);
  float m = fmaxf(fmaxf(v[0],v[1]), fmaxf(v[2],v[3]));
  for (int off=1; off<64; off<<=1) m = fmaxf(m, __shfl_xor(m, off));
  float s = 0.f;
#pragma unroll
  for (int e=0; e<4; e++){ v[e] = __expf(v[e]-m); s += v[e]; }
  for (int off=1; off<64; off<<=1) s += __shfl_xor(s, off);
  float inv = 1.f/s;
  us4 o;
#pragma unroll
  for (int e=0; e<4; e++) o[e] = f2bu(v[e]*inv);
  *(us4*)p = o;
}

__global__ __launch_bounds__(256) void apply_bn_f_k(const u16* __restrict__ x, const float* __restrict__ ss,
                                                    float* __restrict__ out, int n4)
{
  int i = blockIdx.x*256 + threadIdx.x;
  if (i < n4){
    int c0 = (i & 15)*4;
    us4 u = ((const us4*)x)[i];
    float4 o;
    o.x = bf2f(u[0])*ss[c0]   + ss[64+c0];
    o.y = bf2f(u[1])*ss[c0+1] + ss[64+c0+1];
    o.z = bf2f(u[2])*ss[c0+2] + ss[64+c0+2];
    o.w = bf2f(u[3])*ss[c0+3] + ss[64+c0+3];
    ((float4*)out)[i] = o;
  }
}

// ---------------------------------------------------------------------------
extern "C" void kernel_launch(void* const* d_in, const int* in_sizes, int n_in,
                              void* d_out, int out_size, void* d_ws, size_t ws_size,
                              hipStream_t stream)
{
  const float* in    = (const float*)d_in[0];
  const float* wq    = (const float*)d_in[1];  const float* bq    = (const float*)d_in[2];
  const float* wk    = (const float*)d_in[3];  const float* bk    = (const float*)d_in[4];
  const float* wv    = (const float*)d_in[5];  const float* bv    = (const float*)d_in[6];
  const float* gq    = (const float*)d_in[7];  const float* betaq = (const float*)d_in[8];
  const float* gk    = (const float*)d_in[9];  const float* betak = (const float*)d_in[10];
  const float* gv    = (const float*)d_in[11]; const float* betav = (const float*)d_in[12];
  const float* wc    = (const float*)d_in[13]; const float* bcv   = (const float*)d_in[14];
  const float* lng   = (const float*)d_in[15]; const float* lnb   = (const float*)d_in[16];
  const float* w1    = (const float*)d_in[17]; const float* b1    = (const float*)d_in[18];
  const float* g1    = (const float*)d_in[19]; const float* beta1 = (const float*)d_in[20];
  const float* w2    = (const float*)d_in[21]; const float* b2    = (const float*)d_in[22];
  const float* g2    = (const float*)d_in[23]; const float* beta2 = (const float*)d_in[24];
  float* out = (float*)d_out;

  char* ws = (char*)d_ws;
  const size_t MB = 1ull<<20;
  // Layout (reuse only after last read; input never copied):
  //   0..64    qraw -> P1
  //   64..128  kraw -> P2        (P1,P2 contiguous: single softmax launch)
  //   128..192 vraw -> y0(128..144), f1(144..160), rr(160..176)
  //   192..256 qT  --\ cat = 192..320
  //   256..320 kT  --/
  //   320..384 vT   (partial @352, 3MB: conv_qkv writes -> finalize3 reads,
  //                  all before bn_tr3 writes vT; conv2 stats rewrite it after
  //                  vT is dead)
  //   384+     ss (5x128) + prepped weights (~1.2MB)
  u16* qraw = (u16*)(ws);
  u16* kraw = (u16*)(ws + 64*MB);
  u16* vraw = (u16*)(ws + 128*MB);
  u16* qT   = (u16*)(ws + 192*MB);
  u16* kT   = (u16*)(ws + 256*MB);
  u16* vT   = (u16*)(ws + 320*MB);
  u16* P1   = qraw;
  u16* P2   = kraw;
  u16* cat  = qT;
  u16* y0   = (u16*)(ws + 128*MB);
  u16* f1   = (u16*)(ws + 144*MB);
  u16* rr   = (u16*)(ws + 160*MB);
  float* partial = (float*)(ws + 352*MB);            // 3MB (3 x 2048 x 128)
  float* ssq = (float*)(ws + 384*MB);                // ssq,ssk,ssv contiguous
  float* ss1 = ssq + 384;  float* ss2 = ssq + 512;
  u16* wqT = (u16*)(ws + 384*MB + 4096);             // 5 x 36864 contiguous + wcT
  u16* wkT = wqT + 36864; u16* wvT = wkT + 36864;
  u16* w1T = wvT + 36864; u16* w2T = w1T + 36864;
  u16* wcT = w2T + 36864;                            // 294912 elems

  dim3 blk(256);
  dim3 blk768(768);

  prepw5_k<<<dim3(144,5), blk, 0, stream>>>(wq, wk, wv, w1, w2, wqT);
  prepw_k<<<1152, blk, 0, stream>>>(wc, wcT, 512);

  const float invN1 = 1.f/524288.f;
  conv_qkv_f32_k<<<dim3(2,128,8), blk768, 0, stream>>>(in, wqT,wkT,wvT, bq,bk,bv,
                                                       qraw,kraw,vraw, partial);
  finalize3_k<<<3, blk, 0, stream>>>(partial, gq,betaq, gk,betak, gv,betav, invN1, ssq);
  bn_tr3_k<<<dim3(4,256,24), blk, 0, stream>>>(qraw, ssq, qT);

  // scores: time (row-major both), freq (k-major both)
  gemm_k<false,false><<<dim3(2,2,512), blk, 0, stream>>>(qT, kT, P1, 0.0625f, 256, 65536, 0);
  gemm_k<true ,true ><<<dim3(2,2,512), blk, 0, stream>>>(qT, kT, P2, 0.0625f, 256, 65536, 0);
  softmax_k<<<65536, blk, 0, stream>>>(P1);   // P1 and P2 are contiguous
  // AV: time C[t][f] = sum_j P1[t][j] vT[j][f] -> TRB=true
  //     freq C[f][t] = sum_j P2[f][j] vT[t][j] -> TRB=false
  gemm_k<false,true ><<<dim3(2,2,512), blk, 0, stream>>>(P1, vT, cat, 1.f, 512, 131072, 0);
  gemm_k<false,false><<<dim3(2,2,512), blk, 0, stream>>>(P2, vT, cat, 1.f, 512, 131072, 256);

  conv_cat_ln_k<<<dim3(2,32,8), blk, 0, stream>>>(cat, wcT, bcv, lng, lnb, y0);

  const float invN2 = 1.f/131072.f;
  conv2_mfma_k<true,false,true><<<dim3(2,32,8), blk, 0, stream>>>(y0, w1T, b1, ssq, rr, partial);
  finalize512_k<<<1, blk, 0, stream>>>(partial, g1, beta1, invN2, ss1);

  conv2_mfma_k<true,true,true><<<dim3(2,32,8), blk, 0, stream>>>(rr, w2T, b2, ss1, f1, partial);
  finalize512_k<<<1, blk, 0, stream>>>(partial, g2, beta2, invN2, ss2);
  apply_bn_f_k<<<8192, blk, 0, stream>>>(f1, ss2, out, 2097152);
}

// Round 21
// 1024.897 us; speedup vs baseline: 1.1358x; 1.0701x over previous
//
#include <hip/hip_runtime.h>
#include <hip/hip_bf16.h>

typedef unsigned short u16;
typedef u16 us8 __attribute__((ext_vector_type(8)));
typedef u16 us4 __attribute__((ext_vector_type(4)));
typedef __bf16 bfx8 __attribute__((ext_vector_type(8)));
typedef float f32x4 __attribute__((ext_vector_type(4)));

#define EPS 1e-3f

__device__ __forceinline__ float bf2f(u16 u){ unsigned x = ((unsigned)u)<<16; return __builtin_bit_cast(float, x); }
__device__ __forceinline__ u16 f2bu(float f){ __hip_bfloat16 h = __float2bfloat16(f); return __builtin_bit_cast(u16, h); }
__device__ __forceinline__ bfx8 ldb8(const u16* p){ return __builtin_bit_cast(bfx8, *(const us8*)p); }

// direct global->LDS DMA, 16B per lane; LDS dest = wave-uniform base + lane*16B
typedef const __attribute__((address_space(1))) unsigned int cguint;
typedef __attribute__((address_space(3))) unsigned int lduint;
__device__ __forceinline__ void gload16(const u16* g, u16* l){
  __builtin_amdgcn_global_load_lds((cguint*)g, (lduint*)l, 16, 0, 0);
}

// five [9][64][64] f32 weight sets -> [9][64][64] bf16 (co-major), one launch
__global__ __launch_bounds__(256) void prepw5_k(
    const float* __restrict__ w0, const float* __restrict__ w1, const float* __restrict__ w2,
    const float* __restrict__ w3, const float* __restrict__ w4, u16* __restrict__ dst)
{
  int which = blockIdx.y;
  const float* src = which==0?w0:which==1?w1:which==2?w2:which==3?w3:w4;
  u16* d = dst + (size_t)which*36864;
  int idx = blockIdx.x*256 + threadIdx.x;
  if (idx < 36864){
    int ci = idx & 63; int rest = idx >> 6; int co = rest & 63; int t = rest >> 6;
    d[idx] = f2bu(src[((size_t)t*64 + ci)*64 + co]);
  }
}

// weights [9][CI][64] f32 -> [9][64][CI] bf16 (for wc, CI=512)
__global__ __launch_bounds__(256) void prepw_k(const float* __restrict__ src, u16* __restrict__ dst, int CI)
{
  int total = 9*CI*64;
  int idx = blockIdx.x*256 + threadIdx.x;
  if (idx < total){
    int ci = idx % CI; int rest = idx / CI; int co = rest & 63; int t = rest >> 6;
    dst[idx] = f2bu(src[((size_t)t*CI + ci)*64 + co]);
  }
}

// ---------------------------------------------------------------------------
// FUSED q/k/v MFMA 3x3 conv + per-channel stats partials, f32 input NHWC
// block 768 = 3 tensor-groups x 4 waves; tile = 2 rows x 128 x
// XCD-aware block swizzle; outputs staged through LDS -> coalesced 128B stores
// ---------------------------------------------------------------------------
__global__ __launch_bounds__(768) void conv_qkv_f32_k(
    const float* __restrict__ in,
    const u16* __restrict__ WtQ, const u16* __restrict__ WtK, const u16* __restrict__ WtV,
    const float* __restrict__ bq, const float* __restrict__ bk, const float* __restrict__ bv,
    u16* __restrict__ qo, u16* __restrict__ ko, u16* __restrict__ vo,
    float* __restrict__ partial)
{
  // flatten launch grid (2,128,8) -> bijective XCD chunk swizzle (nwg=2048)
  int lin = (blockIdx.z*128 + blockIdx.y)*2 + blockIdx.x;
  int swz = (lin & 7)*256 + (lin >> 3);
  int bx = swz & 1, by = (swz >> 1) & 127, bz = swz >> 8;
  int b = bz, y0 = by*2, x0 = bx*128;
  int tid = threadIdx.x, lane = tid & 63, wid = tid >> 6;   // wid 0..11
  int g3 = wid >> 2, wid4 = wid & 3;
  int l15 = lane & 15, lhi = lane >> 4;
  __shared__ u16 lds[4*130*64];

  for (int idx = tid; idx < 8320; idx += 768){
    int row = idx >> 4, c4 = idx & 15;
    int yy = row / 130, xx = row - yy*130;
    int gy = y0 + yy - 1, gx = x0 + xx - 1;
    us4 v = {0,0,0,0};
    if ((unsigned)gy < 256u && (unsigned)gx < 256u){
      float4 f = *(const float4*)(in + ((((size_t)b*256 + gy)*256 + gx)<<6) + c4*4);
      v[0] = f2bu(f.x); v[1] = f2bu(f.y); v[2] = f2bu(f.z); v[3] = f2bu(f.w);
    }
    *(us4*)(lds + row*64 + ((c4*4) ^ ((xx&7)<<3))) = v;
  }
  __syncthreads();

  const u16*  Wt   = (g3==0) ? WtQ : (g3==1) ? WtK : WtV;
  const float* bias = (g3==0) ? bq  : (g3==1) ? bk  : bv;

  f32x4 acc[2][2][4];
#pragma unroll
  for (int nf=0; nf<4; nf++){
    float bb = bias[nf*16 + l15];
#pragma unroll
    for (int ry=0; ry<2; ry++){
      acc[ry][0][nf] = (f32x4){bb,bb,bb,bb};
      acc[ry][1][nf] = (f32x4){bb,bb,bb,bb};
    }
  }
  int xbase = wid4*32;
#pragma unroll
  for (int ky=0; ky<3; ky++)
#pragma unroll
    for (int kx=0; kx<3; kx++){
      int t = ky*3 + kx;
      bfx8 bfr[2][4];
#pragma unroll
      for (int ks=0; ks<2; ks++)
#pragma unroll
        for (int nf=0; nf<4; nf++)
          bfr[ks][nf] = ldb8(Wt + ((t*64 + nf*16 + l15)<<6) + ks*32 + lhi*8);
#pragma unroll
      for (int ks=0; ks<2; ks++)
#pragma unroll
        for (int ry=0; ry<2; ry++)
#pragma unroll
          for (int mt=0; mt<2; mt++){
            int xx = xbase + mt*16 + l15 + kx;
            bfx8 a = ldb8(lds + ((ry+ky)*130 + xx)*64 + ((ks*32 + lhi*8) ^ ((xx&7)<<3)));
#pragma unroll
            for (int nf=0; nf<4; nf++)
              acc[ry][mt][nf] = __builtin_amdgcn_mfma_f32_16x16x32_bf16(a, bfr[ks][nf], acc[ry][mt][nf], 0,0,0);
          }
    }
  // epilogue: stage outputs in LDS ([3][128][72] u16), coalesced 128B stores
  float s[4] = {0,0,0,0}, qs[4] = {0,0,0,0};
#pragma unroll
  for (int ry=0; ry<2; ry++){
    __syncthreads();
#pragma unroll
    for (int mt=0; mt<2; mt++)
#pragma unroll
      for (int nf=0; nf<4; nf++)
#pragma unroll
        for (int r=0; r<4; r++){
          int xloc = xbase + mt*16 + lhi*4 + r;
          u16 ub = f2bu(acc[ry][mt][nf][r]);
          lds[(g3*128 + xloc)*72 + nf*16 + l15] = ub;
          float vv = bf2f(ub);
          s[nf] += vv; qs[nf] += vv*vv;
        }
    __syncthreads();
    for (int idx = tid; idx < 3072; idx += 768){
      int row = idx >> 3, p8 = idx & 7;           // row = g*128 + xloc
      int g = row >> 7, xloc = row & 127;
      us8 v = *(const us8*)(lds + row*72 + p8*8);
      u16* op = (g==0) ? qo : (g==1) ? ko : vo;
      *(us8*)(op + ((((size_t)b*256 + (y0+ry))*256 + (x0+xloc))<<6) + p8*8) = v;
    }
  }
  __syncthreads();
  float* smS = (float*)lds;          // [48][80] stride-80
  float* smQ = smS + 3840;
#pragma unroll
  for (int nf=0; nf<4; nf++){
    smS[(wid*4 + lhi)*80 + nf*16 + l15] = s[nf];
    smQ[(wid*4 + lhi)*80 + nf*16 + l15] = qs[nf];
  }
  __syncthreads();
  if (tid < 192){
    int tt = tid >> 6, c = tid & 63;
    float ssum = 0.f, qsum = 0.f;
#pragma unroll
    for (int w=0; w<16; w++){
      int slot = (tt*16 + w)*80 + c;
      ssum += smS[slot]; qsum += smQ[slot];
    }
    int blk = swz;                                   // 0..2047 (bijective)
    partial[(size_t)tt*262144 + (size_t)blk*128 + c]      = ssum;
    partial[(size_t)tt*262144 + (size_t)blk*128 + 64 + c] = qsum;
  }
}

// ---------------------------------------------------------------------------
// MFMA 3x3 conv, Cin=Cout=64, bf16 NHWC [8][64][256][64], 2 rows/block (+ReLU)
// BNIN: apply ss-BN to input during staging (reg path); else global_load_lds
// staging with pre-swizzled global source + zero-fill halo. STATS: fused stats.
// ---------------------------------------------------------------------------
template<bool RELU, bool BNIN, bool STATS>
__global__ __launch_bounds__(256) void conv2_mfma_k(
    const u16* __restrict__ in, const u16* __restrict__ Wt, const float* __restrict__ bias,
    const float* __restrict__ ssin, u16* __restrict__ out, float* __restrict__ partial)
{
  int b = blockIdx.z, y0 = blockIdx.y*2, x0 = blockIdx.x*128;
  int tid = threadIdx.x, lane = tid & 63, wid = tid >> 6;
  int l15 = lane & 15, lhi = lane >> 4;
  __shared__ u16 lds[4*130*64];
  __shared__ float ssm[128];
  if (BNIN){
    if (tid < 128) ssm[tid] = ssin[tid];
    __syncthreads();
  }

  if (!BNIN){
    // DMA staging: slot s of row holds global colgroup s ^ (xx&7); halo -> 0
    for (int it = 0; it < 17; it++){
      int rb = it*32 + wid*8;                 // wave-uniform row base
      if (rb < 520){
        int row = rb + (lane >> 3);
        int c8s = lane & 7;
        int yy = row / 130, xx = row - yy*130;
        int gy = y0 + yy - 1, gx = x0 + xx - 1;
        int cg = c8s ^ (xx & 7);
        if ((unsigned)gy < 64u && (unsigned)gx < 256u)
          gload16(in + ((((size_t)b*64 + gy)*256 + gx)<<6) + cg*8, lds + rb*64);
        else
          *(us8*)(lds + row*64 + c8s*8) = (us8){0,0,0,0,0,0,0,0};
      }
    }
  } else {
    for (int idx = tid; idx < 4160; idx += 256){
      int row = idx >> 3, ch = idx & 7;
      int yy = row / 130, xx = row - yy*130;
      int gy = y0 + yy - 1, gx = x0 + xx - 1;
      us8 w = {0,0,0,0,0,0,0,0};
      if ((unsigned)gy < 64u && (unsigned)gx < 256u){
        us8 v = *(const us8*)(in + ((((size_t)b*64 + gy)*256 + gx)<<6) + ch*8);
#pragma unroll
        for (int e=0; e<8; e++){
          int ci = ch*8 + e;
          w[e] = f2bu(bf2f(v[e])*ssm[ci] + ssm[64+ci]);
        }
      }
      *(us8*)(lds + row*64 + ((ch*8) ^ ((xx&7)<<3))) = w;
    }
  }
  __syncthreads();

  f32x4 acc[2][2][4];
#pragma unroll
  for (int nf=0; nf<4; nf++){
    float bb = bias[nf*16 + l15];
#pragma unroll
    for (int ry=0; ry<2; ry++){
      acc[ry][0][nf] = (f32x4){bb,bb,bb,bb};
      acc[ry][1][nf] = (f32x4){bb,bb,bb,bb};
    }
  }
  int xbase = wid*32;
#pragma unroll
  for (int ky=0; ky<3; ky++)
#pragma unroll
    for (int kx=0; kx<3; kx++){
      int t = ky*3 + kx;
      bfx8 bfr[2][4];
#pragma unroll
      for (int ks=0; ks<2; ks++)
#pragma unroll
        for (int nf=0; nf<4; nf++)
          bfr[ks][nf] = ldb8(Wt + ((t*64 + nf*16 + l15)<<6) + ks*32 + lhi*8);
#pragma unroll
      for (int ks=0; ks<2; ks++)
#pragma unroll
        for (int ry=0; ry<2; ry++)
#pragma unroll
          for (int mt=0; mt<2; mt++){
            int xx = xbase + mt*16 + l15 + kx;
            bfx8 a = ldb8(lds + ((ry+ky)*130 + xx)*64 + ((ks*32 + lhi*8) ^ ((xx&7)<<3)));
#pragma unroll
            for (int nf=0; nf<4; nf++)
              acc[ry][mt][nf] = __builtin_amdgcn_mfma_f32_16x16x32_bf16(a, bfr[ks][nf], acc[ry][mt][nf], 0,0,0);
          }
    }
  float s[4] = {0,0,0,0}, qs[4] = {0,0,0,0};
#pragma unroll
  for (int ry=0; ry<2; ry++)
#pragma unroll
    for (int mt=0; mt<2; mt++)
#pragma unroll
      for (int nf=0; nf<4; nf++)
#pragma unroll
        for (int r=0; r<4; r++){
          int x = x0 + xbase + mt*16 + lhi*4 + r;
          float vv = acc[ry][mt][nf][r];
          if (RELU) vv = fmaxf(vv, 0.f);
          u16 ub = f2bu(vv);
          out[((((size_t)b*64 + (y0+ry))*256 + x)<<6) + nf*16 + l15] = ub;
          if (STATS){
            float vb = bf2f(ub);
            s[nf] += vb; qs[nf] += vb*vb;
          }
        }
  if (STATS){
    __syncthreads();
    float* smS = (float*)lds;        // [16][80] stride-80
    float* smQ = smS + 1280;
#pragma unroll
    for (int nf=0; nf<4; nf++){
      smS[(wid*4 + lhi)*80 + nf*16 + l15] = s[nf];
      smQ[(wid*4 + lhi)*80 + nf*16 + l15] = qs[nf];
    }
    __syncthreads();
    if (tid < 64){
      float ssum = 0.f, qsum = 0.f;
#pragma unroll
      for (int w=0; w<16; w++){
        ssum += smS[w*80 + tid]; qsum += smQ[w*80 + tid];
      }
      int blk = (blockIdx.z*32 + blockIdx.y)*2 + blockIdx.x;   // 0..511
      partial[(size_t)blk*128 + tid]      = ssum;
      partial[(size_t)blk*128 + 64 + tid] = qsum;
    }
  }
}

// ---------------------------------------------------------------------------
// MFMA conv on cat [8][64][256][512] -> +bias -> LayerNorm(64), 2 rows/block
// staging via global_load_lds with pre-swizzled global source + zero halo
// ---------------------------------------------------------------------------
__global__ __launch_bounds__(256) void conv_cat_ln_k(
    const u16* __restrict__ in, const u16* __restrict__ Wt, const float* __restrict__ bias,
    const float* __restrict__ lng, const float* __restrict__ lnb, u16* __restrict__ out)
{
  int b = blockIdx.z, y0 = blockIdx.y*2, x0 = blockIdx.x*128;
  int tid = threadIdx.x, lane = tid & 63, wid = tid >> 6;
  int l15 = lane & 15, lhi = lane >> 4;
  __shared__ u16 lds[4*130*64];

  f32x4 acc[2][2][4];
#pragma unroll
  for (int nf=0; nf<4; nf++){
    float bb = bias[nf*16 + l15];
#pragma unroll
    for (int ry=0; ry<2; ry++){
      acc[ry][0][nf] = (f32x4){bb,bb,bb,bb};
      acc[ry][1][nf] = (f32x4){bb,bb,bb,bb};
    }
  }
  int xbase = wid*32;
  for (int ci0 = 0; ci0 < 512; ci0 += 64){
    __syncthreads();
    for (int it = 0; it < 17; it++){
      int rb = it*32 + wid*8;                 // wave-uniform row base
      if (rb < 520){
        int row = rb + (lane >> 3);
        int c8s = lane & 7;
        int yy = row / 130, xx = row - yy*130;
        int gy = y0 + yy - 1, gx = x0 + xx - 1;
        int cg = c8s ^ (xx & 7);
        if ((unsigned)gy < 64u && (unsigned)gx < 256u)
          gload16(in + ((((size_t)b*64 + gy)*256 + gx)<<9) + ci0 + cg*8, lds + rb*64);
        else
          *(us8*)(lds + row*64 + c8s*8) = (us8){0,0,0,0,0,0,0,0};
      }
    }
    __syncthreads();
#pragma unroll
    for (int ky=0; ky<3; ky++)
#pragma unroll
      for (int kx=0; kx<3; kx++){
        int t = ky*3 + kx;
        bfx8 bfr[2][4];
#pragma unroll
        for (int ks=0; ks<2; ks++)
#pragma unroll
          for (int nf=0; nf<4; nf++)
            bfr[ks][nf] = ldb8(Wt + ((size_t)(t*64 + nf*16 + l15)<<9) + ci0 + ks*32 + lhi*8);
#pragma unroll
        for (int ks=0; ks<2; ks++)
#pragma unroll
          for (int ry=0; ry<2; ry++)
#pragma unroll
            for (int mt=0; mt<2; mt++){
              int xx = xbase + mt*16 + l15 + kx;
              bfx8 a = ldb8(lds + ((ry+ky)*130 + xx)*64 + ((ks*32 + lhi*8) ^ ((xx&7)<<3)));
#pragma unroll
              for (int nf=0; nf<4; nf++)
                acc[ry][mt][nf] = __builtin_amdgcn_mfma_f32_16x16x32_bf16(a, bfr[ks][nf], acc[ry][mt][nf], 0,0,0);
            }
      }
  }
  float lg[4], lb[4];
#pragma unroll
  for (int nf=0; nf<4; nf++){ lg[nf] = lng[nf*16+l15]; lb[nf] = lnb[nf*16+l15]; }
#pragma unroll
  for (int ry=0; ry<2; ry++)
#pragma unroll
    for (int mt=0; mt<2; mt++)
#pragma unroll
      for (int r=0; r<4; r++){
        float v0 = acc[ry][mt][0][r], v1 = acc[ry][mt][1][r], v2 = acc[ry][mt][2][r], v3 = acc[ry][mt][3][r];
        float s = v0+v1+v2+v3;
        s += __shfl_xor(s,1); s += __shfl_xor(s,2); s += __shfl_xor(s,4); s += __shfl_xor(s,8);
        float m = s * 0.015625f;
        float d0=v0-m, d1=v1-m, d2=v2-m, d3=v3-m;
        float q = d0*d0+d1*d1+d2*d2+d3*d3;
        q += __shfl_xor(q,1); q += __shfl_xor(q,2); q += __shfl_xor(q,4); q += __shfl_xor(q,8);
        float rs = rsqrtf(q*0.015625f + EPS);
        int x = x0 + xbase + mt*16 + lhi*4 + r;
        size_t base = ((((size_t)b*64 + (y0+ry))*256 + x)<<6) + l15;
        out[base]    = f2bu(d0*rs*lg[0] + lb[0]);
        out[base+16] = f2bu(d1*rs*lg[1] + lb[1]);
        out[base+32] = f2bu(d2*rs*lg[2] + lb[2]);
        out[base+48] = f2bu(d3*rs*lg[3] + lb[3]);
      }
}

// grid 3: block tt finalizes tensor tt's 2048 partials (from conv_qkv epilogue)
__global__ __launch_bounds__(256) void finalize3_k(const float* __restrict__ partial,
    const float* __restrict__ gq, const float* __restrict__ bq,
    const float* __restrict__ gk, const float* __restrict__ bk,
    const float* __restrict__ gv, const float* __restrict__ bv,
    float inv_count, float* __restrict__ ssbase)
{
  int tt = blockIdx.x;
  const float* part = partial + (size_t)tt*262144;
  const float* g  = (tt==0)?gq:(tt==1)?gk:gv;
  const float* be = (tt==0)?bq:(tt==1)?bk:bv;
  float* ss = ssbase + tt*128;
  __shared__ float sm[4][128];
  int c = threadIdx.x & 63, qq = threadIdx.x >> 6;
  float s = 0.f, v = 0.f;
  for (int i = qq*512; i < qq*512+512; i++){ s += part[i*128 + c]; v += part[i*128 + 64 + c]; }
  sm[qq][c] = s; sm[qq][64+c] = v;
  __syncthreads();
  if (qq == 0){
    s = sm[0][c]+sm[1][c]+sm[2][c]+sm[3][c];
    v = sm[0][64+c]+sm[1][64+c]+sm[2][64+c]+sm[3][64+c];
    float m = s*inv_count;
    float var = v*inv_count - m*m;
    float sc = g[c]*rsqrtf(var + EPS);
    ss[c] = sc; ss[64+c] = be[c] - m*sc;
  }
}

// finalizes 512 partials (from conv2 fused stats)
__global__ __launch_bounds__(256) void finalize512_k(const float* __restrict__ partial,
                                                     const float* __restrict__ g, const float* __restrict__ beta,
                                                     float inv_count, float* __restrict__ ss)
{
  __shared__ float sm[4][128];
  int c = threadIdx.x & 63, qq = threadIdx.x >> 6;
  float s = 0.f, v = 0.f;
  for (int i = qq*128; i < qq*128+128; i++){ s += partial[i*128 + c]; v += partial[i*128 + 64 + c]; }
  sm[qq][c] = s; sm[qq][64+c] = v;
  __syncthreads();
  if (qq == 0){
    s = sm[0][c]+sm[1][c]+sm[2][c]+sm[3][c];
    v = sm[0][64+c]+sm[1][64+c]+sm[2][64+c]+sm[3][64+c];
    float m = s*inv_count;
    float var = v*inv_count - m*m;
    float sc = g[c]*rsqrtf(var + EPS);
    ss[c] = sc; ss[64+c] = beta[c] - m*sc;
  }
}

// ---------------------------------------------------------------------------
// BN-fused transpose, all 3 tensors in one launch; us8 global r/w
// grid (4, 256, 24): z -> tt = z>>3 (tensor), b = z&7
__global__ __launch_bounds__(256) void bn_tr3_k(const u16* __restrict__ xbase,
                                                const float* __restrict__ ssbase,
                                                u16* __restrict__ xTbase)
{
  int z = blockIdx.z, tt = z >> 3, b = z & 7;
  const u16* x = xbase + (size_t)tt*33554432;
  const float* ss = ssbase + tt*128;
  u16* xT = xTbase + (size_t)tt*33554432;
  int t = blockIdx.y, f0 = blockIdx.x*64;
  __shared__ float sm[64][65];
  int tid = threadIdx.x;
  for (int idx = tid; idx < 512; idx += 256){
    int fi = idx >> 3, cg = idx & 7;
    us8 v = *(const us8*)(x + ((((size_t)b*256 + t)*256 + f0 + fi)<<6) + cg*8);
#pragma unroll
    for (int e=0; e<8; e++){
      int ci = cg*8 + e;
      sm[fi][ci] = bf2f(v[e])*ss[ci] + ss[64+ci];
    }
  }
  __syncthreads();
  for (int idx = tid; idx < 512; idx += 256){
    int ci = idx >> 3, fg = idx & 7;
    us8 o;
#pragma unroll
    for (int e=0; e<8; e++) o[e] = f2bu(sm[fg*8+e][ci]);
    *(us8*)(xT + (((size_t)b*64 + ci)<<16) + t*256 + f0 + fg*8) = o;
  }
}

// ---------------------------------------------------------------------------
// MFMA GEMM: C[bc][i][n] = scale * sum_k A(i,k)*B(n,k), 256x256x256 per bc
// non-transposed operand staging via global_load_lds (linear LDS dest,
// swizzle applied to the per-lane GLOBAL source; read side unchanged)
template<bool TRA, bool TRB>
__global__ __launch_bounds__(256) void gemm_k(const u16* __restrict__ A, const u16* __restrict__ B,
                                              u16* __restrict__ C, float scale,
                                              int ldC, size_t cBatch, int cOff)
{
  int bc = blockIdx.z;
  const u16* Ab = A + ((size_t)bc<<16);
  const u16* Bb = B + ((size_t)bc<<16);
  u16* Cb = C + (size_t)bc*cBatch + cOff;
  int i0 = blockIdx.y*128, j0 = blockIdx.x*128;
  int tid = threadIdx.x, lane = tid & 63, wid = tid >> 6;
  int l15 = lane & 15, lhi = lane >> 4;
  __shared__ u16 Al[128*64], Bl[128*64];
  f32x4 acc[2][8] = {};

  int r_off = lane >> 3, c8g = lane & 7;    // lane -> (row-in-8, colgroup)

  for (int k0 = 0; k0 < 256; k0 += 64){
    __syncthreads();
    if (!TRA){
#pragma unroll
      for (int it = 0; it < 4; it++){
        int rb = it*32 + wid*8;
        int r  = rb + r_off;
        gload16(Ab + (size_t)(i0+r)*256 + k0 + 8*(c8g ^ (r&7)), Al + rb*64);
      }
    } else {
      for (int idx = tid; idx < 1024; idx += 256){
        int kr = idx >> 4, c8 = idx & 15;
        us8 v = *(const us8*)(Ab + (size_t)(k0+kr)*256 + i0 + c8*8);
#pragma unroll
        for (int e=0; e<8; e++){
          int i = c8*8 + e;
          Al[i*64 + (kr ^ ((i&7)<<3))] = v[e];
        }
      }
    }
    if (!TRB){
#pragma unroll
      for (int it = 0; it < 4; it++){
        int rb = it*32 + wid*8;
        int r  = rb + r_off;
        gload16(Bb + (size_t)(j0+r)*256 + k0 + 8*(c8g ^ (r&7)), Bl + rb*64);
      }
    } else {
      for (int idx = tid; idx < 1024; idx += 256){
        int kr = idx >> 4, c8 = idx & 15;
        us8 v = *(const us8*)(Bb + (size_t)(k0+kr)*256 + j0 + c8*8);
#pragma unroll
        for (int e=0; e<8; e++){
          int j = c8*8 + e;
          Bl[j*64 + (kr ^ ((j&7)<<3))] = v[e];
        }
      }
    }
    __syncthreads();
    int wrow = wid*32;
#pragma unroll
    for (int ks=0; ks<2; ks++){
      bfx8 bfr[8];
#pragma unroll
      for (int nf=0; nf<8; nf++)
        bfr[nf] = ldb8(Bl + (nf*16+l15)*64 + ((ks*32 + lhi*8) ^ ((l15&7)<<3)));
#pragma unroll
      for (int mt=0; mt<2; mt++){
        int r = wrow + mt*16 + l15;
        bfx8 a = ldb8(Al + r*64 + ((ks*32 + lhi*8) ^ ((r&7)<<3)));
#pragma unroll
        for (int nf=0; nf<8; nf++)
          acc[mt][nf] = __builtin_amdgcn_mfma_f32_16x16x32_bf16(a, bfr[nf], acc[mt][nf], 0,0,0);
      }
    }
  }
#pragma unroll
  for (int mt=0; mt<2; mt++)
#pragma unroll
    for (int nf=0; nf<8; nf++)
#pragma unroll
      for (int r=0; r<4; r++){
        int i = i0 + wid*32 + mt*16 + lhi*4 + r;
        int j = j0 + nf*16 + l15;
        Cb[(size_t)i*ldC + j] = f2bu(acc[mt][nf][r]*scale);
      }
}

// softmax over rows of 256 (one wave per row), in-place
__global__ __launch_bounds__(256) void softmax_k(u16* __restrict__ P)
{
  size_t row = (size_t)blockIdx.x*4 + (threadIdx.x >> 6);
  int lane = threadIdx.x & 63;
  u16* p = P + row*256 + lane*4;
  us4 u = *(us4*)p;
  float v[4];
#pragma unroll
  for (int e=0; e<4; e++) v[e] = bf2f(u[e]);
  float m = fmaxf(fmaxf(v[0],v[1]), fmaxf(v[2],v[3]));
  for (int off=1; off<64; off<<=1) m = fmaxf(m, __shfl_xor(m, off));
  float s = 0.f;
#pragma unroll
  for (int e=0; e<4; e++){ v[e] = __expf(v[e]-m); s += v[e]; }
  for (int off=1; off<64; off<<=1) s += __shfl_xor(s, off);
  float inv = 1.f/s;
  us4 o;
#pragma unroll
  for (int e=0; e<4; e++) o[e] = f2bu(v[e]*inv);
  *(us4*)p = o;
}

__global__ __launch_bounds__(256) void apply_bn_f_k(const u16* __restrict__ x, const float* __restrict__ ss,
                                                    float* __restrict__ out, int n4)
{
  int i = blockIdx.x*256 + threadIdx.x;
  if (i < n4){
    int c0 = (i & 15)*4;
    us4 u = ((const us4*)x)[i];
    float4 o;
    o.x = bf2f(u[0])*ss[c0]   + ss[64+c0];
    o.y = bf2f(u[1])*ss[c0+1] + ss[64+c0+1];
    o.z = bf2f(u[2])*ss[c0+2] + ss[64+c0+2];
    o.w = bf2f(u[3])*ss[c0+3] + ss[64+c0+3];
    ((float4*)out)[i] = o;
  }
}

// ---------------------------------------------------------------------------
extern "C" void kernel_launch(void* const* d_in, const int* in_sizes, int n_in,
                              void* d_out, int out_size, void* d_ws, size_t ws_size,
                              hipStream_t stream)
{
  const float* in    = (const float*)d_in[0];
  const float* wq    = (const float*)d_in[1];  const float* bq    = (const float*)d_in[2];
  const float* wk    = (const float*)d_in[3];  const float* bk    = (const float*)d_in[4];
  const float* wv    = (const float*)d_in[5];  const float* bv    = (const float*)d_in[6];
  const float* gq    = (const float*)d_in[7];  const float* betaq = (const float*)d_in[8];
  const float* gk    = (const float*)d_in[9];  const float* betak = (const float*)d_in[10];
  const float* gv    = (const float*)d_in[11]; const float* betav = (const float*)d_in[12];
  const float* wc    = (const float*)d_in[13]; const float* bcv   = (const float*)d_in[14];
  const float* lng   = (const float*)d_in[15]; const float* lnb   = (const float*)d_in[16];
  const float* w1    = (const float*)d_in[17]; const float* b1    = (const float*)d_in[18];
  const float* g1    = (const float*)d_in[19]; const float* beta1 = (const float*)d_in[20];
  const float* w2    = (const float*)d_in[21]; const float* b2    = (const float*)d_in[22];
  const float* g2    = (const float*)d_in[23]; const float* beta2 = (const float*)d_in[24];
  float* out = (float*)d_out;

  char* ws = (char*)d_ws;
  const size_t MB = 1ull<<20;
  // Layout (reuse only after last read; input never copied):
  //   0..64    qraw -> P1
  //   64..128  kraw -> P2        (P1,P2 contiguous: single softmax launch)
  //   128..192 vraw -> y0(128..144), f1(144..160), rr(160..176)
  //   192..256 qT  --\ cat = 192..320
  //   256..320 kT  --/
  //   320..384 vT   (partial @352, 3MB: conv_qkv writes -> finalize3 reads,
  //                  all before bn_tr3 writes vT; conv2 stats rewrite it after
  //                  vT is dead)
  //   384+     ss (5x128) + prepped weights (~1.2MB)
  u16* qraw = (u16*)(ws);
  u16* kraw = (u16*)(ws + 64*MB);
  u16* vraw = (u16*)(ws + 128*MB);
  u16* qT   = (u16*)(ws + 192*MB);
  u16* kT   = (u16*)(ws + 256*MB);
  u16* vT   = (u16*)(ws + 320*MB);
  u16* P1   = qraw;
  u16* P2   = kraw;
  u16* cat  = qT;
  u16* y0   = (u16*)(ws + 128*MB);
  u16* f1   = (u16*)(ws + 144*MB);
  u16* rr   = (u16*)(ws + 160*MB);
  float* partial = (float*)(ws + 352*MB);            // 3MB (3 x 2048 x 128)
  float* ssq = (float*)(ws + 384*MB);                // ssq,ssk,ssv contiguous
  float* ss1 = ssq + 384;  float* ss2 = ssq + 512;
  u16* wqT = (u16*)(ws + 384*MB + 4096);             // 5 x 36864 contiguous + wcT
  u16* wkT = wqT + 36864; u16* wvT = wkT + 36864;
  u16* w1T = wvT + 36864; u16* w2T = w1T + 36864;
  u16* wcT = w2T + 36864;                            // 294912 elems

  dim3 blk(256);
  dim3 blk768(768);

  prepw5_k<<<dim3(144,5), blk, 0, stream>>>(wq, wk, wv, w1, w2, wqT);
  prepw_k<<<1152, blk, 0, stream>>>(wc, wcT, 512);

  const float invN1 = 1.f/524288.f;
  conv_qkv_f32_k<<<dim3(2,128,8), blk768, 0, stream>>>(in, wqT,wkT,wvT, bq,bk,bv,
                                                       qraw,kraw,vraw, partial);
  finalize3_k<<<3, blk, 0, stream>>>(partial, gq,betaq, gk,betak, gv,betav, invN1, ssq);
  bn_tr3_k<<<dim3(4,256,24), blk, 0, stream>>>(qraw, ssq, qT);

  // scores: time (row-major both), freq (k-major both)
  gemm_k<false,false><<<dim3(2,2,512), blk, 0, stream>>>(qT, kT, P1, 0.0625f, 256, 65536, 0);
  gemm_k<true ,true ><<<dim3(2,2,512), blk, 0, stream>>>(qT, kT, P2, 0.0625f, 256, 65536, 0);
  softmax_k<<<65536, blk, 0, stream>>>(P1);   // P1 and P2 are contiguous
  // AV: time C[t][f] = sum_j P1[t][j] vT[j][f] -> TRB=true
  //     freq C[f][t] = sum_j P2[f][j] vT[t][j] -> TRB=false
  gemm_k<false,true ><<<dim3(2,2,512), blk, 0, stream>>>(P1, vT, cat, 1.f, 512, 131072, 0);
  gemm_k<false,false><<<dim3(2,2,512), blk, 0, stream>>>(P2, vT, cat, 1.f, 512, 131072, 256);

  conv_cat_ln_k<<<dim3(2,32,8), blk, 0, stream>>>(cat, wcT, bcv, lng, lnb, y0);

  const float invN2 = 1.f/131072.f;
  conv2_mfma_k<true,false,true><<<dim3(2,32,8), blk, 0, stream>>>(y0, w1T, b1, ssq, rr, partial);
  finalize512_k<<<1, blk, 0, stream>>>(partial, g1, beta1, invN2, ss1);

  conv2_mfma_k<true,true,true><<<dim3(2,32,8), blk, 0, stream>>>(rr, w2T, b2, ss1, f1, partial);
  finalize512_k<<<1, blk, 0, stream>>>(partial, g2, beta2, invN2, ss2);
  apply_bn_f_k<<<8192, blk, 0, stream>>>(f1, ss2, out, 2097152);
}